// Round 4
// baseline (209.241 us; speedup 1.0000x reference)
//
#include <hip/hip_runtime.h>

namespace {

constexpr int H = 512;
constexpr int W = 512;
constexpr int HW = H * W;
constexpr int PPS = 8;    // planes per canny set
constexpr int NP = 16;    // total planes (2 sets x 8)
constexpr int TX = 64;    // tile width (dnms/result)
constexpr int TY = 8;     // tile height (dnms/result)
constexpr int NBLK = (W / TX) * (H / TY) * NP;   // 8192
constexpr float PI_F = 3.14159265358979323846f;

// smooth3 tile: 16 rows x 64 cols output, halo 6 each side
constexpr int S3_TY = 16;
constexpr int S3_R = S3_TY + 12;   // 28
constexpr int S3_C = 64 + 12;      // 76

__device__ __forceinline__ float hsw(float x) {
    float t = fminf(fmaxf(x + 3.0f, 0.0f), 6.0f);
    return x * t * (1.0f / 6.0f);
}

__device__ __forceinline__ const float* plane_ptr(const float* s1, const float* s2, int p) {
    return (p < PPS) ? (s1 + (size_t)p * HW) : (s2 + (size_t)(p - PPS) * HW);
}

__device__ __forceinline__ float wave_max(float v) {
    for (int o = 32; o > 0; o >>= 1) v = fmaxf(v, __shfl_down(v, o, 64));
    return v;
}
__device__ __forceinline__ float wave_min(float v) {
    for (int o = 32; o > 0; o >>= 1) v = fminf(v, __shfl_down(v, o, 64));
    return v;
}

// minimax atan on [0,1], err ~2e-7
__device__ __forceinline__ float atan_poly(float t) {
    float z = t * t;
    float p = -0.01172120f;
    p = p * z + 0.05265332f;
    p = p * z - 0.11643287f;
    p = p * z + 0.19354346f;
    p = p * z - 0.33262347f;
    p = p * z + 0.99997726f;
    return t * p;
}

__global__ void K_init(unsigned* hist, unsigned* prefix, int* krem) {
    int t = threadIdx.x;
    for (int i = t; i < NP * 2048; i += 256) hist[i] = 0;
    if (t < NP) { prefix[t] = 0; krem[t] = (HW - 1) / 2; }
}

// All 3 adaptive-smoothing iterations fused in LDS (exact clip semantics).
__global__ void K_smooth3(const float* __restrict__ s1, const float* __restrict__ s2,
                          float* __restrict__ fout) {
    int p = blockIdx.z;
    const float* f = plane_ptr(s1, s2, p);
    int j0 = blockIdx.x * 64, i0 = blockIdx.y * S3_TY;
    __shared__ float bufA[S3_R][S3_C], bufB[S3_R][S3_C], wbuf[S3_R][S3_C];
    int tid = threadIdx.y * 64 + threadIdx.x;

    for (int e = tid; e < S3_R * S3_C; e += 256) {
        int y = e / S3_C, x = e % S3_C;
        int gi = min(max(i0 - 6 + y, 0), H - 1);
        int gj = min(max(j0 - 6 + x, 0), W - 1);
        bufA[y][x] = f[gi * W + gj];
    }
    __syncthreads();

    float (*src)[S3_C] = bufA;
    float (*dst)[S3_C] = bufB;
    for (int k = 0; k < 3; k++) {
        // w on rows 1..26, cols 1..74 (fixed range; halo garbage never consumed)
        for (int e = tid; e < 26 * 74; e += 256) {
            int y = 1 + e / 74, x = 1 + e % 74;
            int r = min(max(i0 - 6 + y, 0), H - 1);
            int c = min(max(j0 - 6 + x, 0), W - 1);
            int yr = r - (i0 - 6), xc = c - (j0 - 6);
            int ym = max(r - 1, 0) - (i0 - 6), yp = min(r + 1, H - 1) - (i0 - 6);
            int xm = max(c - 1, 0) - (j0 - 6), xp = min(c + 1, W - 1) - (j0 - 6);
            float gx = 0.5f * (src[yp][xc] - src[ym][xc]);
            float gy = 0.5f * (src[yr][xp] - src[yr][xm]);
            wbuf[y][x] = __expf(-(gx * gx + gy * gy) * (1.0f / 200.0f));
        }
        __syncthreads();
        // f on rows 2..25, cols 2..73
        for (int e = tid; e < 24 * 72; e += 256) {
            int y = 2 + e / 72, x = 2 + e % 72;
            int r = min(max(i0 - 6 + y, 0), H - 1);
            int c = min(max(j0 - 6 + x, 0), W - 1);
            int ra0 = max(r - 1, 0) - (i0 - 6), ra1 = r - (i0 - 6), ra2 = min(r + 1, H - 1) - (i0 - 6);
            int cb0 = max(c - 1, 0) - (j0 - 6), cb1 = c - (j0 - 6), cb2 = min(c + 1, W - 1) - (j0 - 6);
            int ra[3] = {ra0, ra1, ra2};
            int cb[3] = {cb0, cb1, cb2};
            float num = 0.0f, den = 0.0f;
            for (int a = 0; a < 3; a++)
                for (int b = 0; b < 3; b++) {
                    float wv = wbuf[ra[a]][cb[b]];
                    num += src[ra[a]][cb[b]] * wv;
                    den += wv;
                }
            dst[y][x] = num / fmaxf(den, 1e-8f);
        }
        __syncthreads();
        float (*tmp)[S3_C] = src; src = dst; dst = tmp;
    }
    // src holds f3, valid on [6, 6+S3_TY) x [6, 70)
    for (int e = tid; e < S3_TY * 64; e += 256) {
        int y = e / 64, x = e % 64;
        fout[(size_t)p * HW + (i0 + y) * W + (j0 + x)] = src[6 + y][6 + x];
    }
}

// fused derivatives + NMS + sob write + median pass-0 histogram
__global__ void K_dnms(const float* __restrict__ blur, float* __restrict__ sup,
                       float* __restrict__ sob, unsigned* __restrict__ hist,
                       float* __restrict__ pmax) {
    int p = blockIdx.z;
    const float* f = blur + (size_t)p * HW;
    int j0 = blockIdx.x * TX, i0 = blockIdx.y * TY;
    __shared__ float fs[TY + 4][TX + 4];        // blur at clipped coords, halo 2
    __shared__ float ms[TY + 2][TX + 2];        // mag at clipped coords (replicate pad)
    __shared__ float exs[TY][TX], eys[TY][TX];  // interior zero-pad sobel components
    __shared__ unsigned histS[2048];
    __shared__ float wred[4];
    int tid = threadIdx.y * 64 + threadIdx.x;

    for (int e = tid; e < 2048; e += 256) histS[e] = 0;
    for (int e = tid; e < (TY + 4) * (TX + 4); e += 256) {
        int y = e / (TX + 4), x = e % (TX + 4);
        int gi = min(max(i0 - 2 + y, 0), H - 1);
        int gj = min(max(j0 - 2 + x, 0), W - 1);
        fs[y][x] = f[gi * W + gj];
    }
    __syncthreads();

    auto tap = [&](int rr, int cc) -> float {
        return (rr >= 0 && rr < H && cc >= 0 && cc < W) ? fs[rr - i0 + 2][cc - j0 + 2] : 0.0f;
    };

    for (int e = tid; e < (TY + 2) * (TX + 2); e += 256) {
        int y = e / (TX + 2), x = e % (TX + 2);
        int r = min(max(i0 - 1 + y, 0), H - 1);
        int c = min(max(j0 - 1 + x, 0), W - 1);
        float xmm = tap(r - 1, c - 1), xm0 = tap(r - 1, c), xmp = tap(r - 1, c + 1);
        float x0m = tap(r, c - 1), x0p = tap(r, c + 1);
        float xpm = tap(r + 1, c - 1), xp0 = tap(r + 1, c), xpp = tap(r + 1, c + 1);
        float ex = (xmp - xmm) + 2.0f * (x0p - x0m) + (xpp - xpm);
        float ey = (xpm + 2.0f * xp0 + xpp) - (xmm + 2.0f * xm0 + xmp);
        float e45 = -2.0f * xmm - xm0 - x0m + x0p + xp0 + 2.0f * xpp;
        float e135 = xm0 + 2.0f * xmp - x0m + x0p - 2.0f * xpm - xp0;
        ms[y][x] = sqrtf(ex * ex + ey * ey + e45 * e45 + e135 * e135);
        if (y >= 1 && y <= TY && x >= 1 && x <= TX) {
            exs[y - 1][x - 1] = ex;
            eys[y - 1][x - 1] = ey;
        }
    }
    __syncthreads();

    float bmax = 0.0f;
    for (int q = 0; q < TY / 4; q++) {
        int yl = threadIdx.y + q * 4;
        int xl = threadIdx.x;
        float ex = exs[yl][xl], ey = eys[yl][xl];

        // fast mod-pi line angle
        float ax = fabsf(ex), ay = fabsf(ey);
        float mn = fminf(ax, ay), mxv = fmaxf(ax, ay);
        float t = (mxv > 0.0f) ? __fdividef(mn, mxv) : 0.0f;
        float pang = atan_poly(t);
        if (ay > ax) pang = 1.57079632679f - pang;
        bool obtuse = ((__float_as_uint(ex) ^ __float_as_uint(ey)) & 0x80000000u) != 0u;
        float a = obtuse ? PI_F - pang : pang;

        // direction weights: softmax(-100*circdist) without max-sub (bounded)
        float d0 = fminf(a, PI_F - a);
        float t1 = fabsf(a - 0.78539816340f); float d1 = fminf(t1, PI_F - t1);
        float t2 = fabsf(a - 1.57079632679f); float d2 = fminf(t2, PI_F - t2);
        float t3 = fabsf(a - 2.35619449019f); float d3 = fminf(t3, PI_F - t3);
        float e0 = __expf(d0 * -100.0f), e1 = __expf(d1 * -100.0f);
        float e2 = __expf(d2 * -100.0f), e3 = __expf(d3 * -100.0f);
        float winv = __fdividef(1.0f, e0 + e1 + e2 + e3);

        float m0 = ms[yl + 1][xl + 1];
        float n1s[4] = {ms[yl + 1][xl], ms[yl][xl], ms[yl][xl + 1], ms[yl][xl + 2]};
        float n2s[4] = {ms[yl + 1][xl + 2], ms[yl + 2][xl + 2], ms[yl + 2][xl + 1], ms[yl + 2][xl]};
        float dws[4] = {e0, e1, e2, e3};

        float sAcc = 0.0f;
        for (int d = 0; d < 4; d++) {
            float g1 = __expf((n1s[d] - m0) * 10.0f);
            float g2 = __expf((n2s[d] - m0) * 10.0f);
            float sw = __fdividef(1.0f, 1.0f + g1 + g2);
            sAcc += sw * dws[d];
        }
        float s = m0 * sAcc * winv;
        size_t gidx = (size_t)p * HW + (i0 + yl) * W + (j0 + xl);
        sup[gidx] = s;
        bmax = fmaxf(bmax, s);

        // median pass 0: sob value + LDS histogram (top 11 bits)
        float sv = 0.5f * (ax + ay);
        sob[gidx] = sv;
        atomicAdd(&histS[__float_as_uint(sv) >> 21], 1u);
    }

    float wv = wave_max(bmax);
    if ((tid & 63) == 0) wred[tid >> 6] = wv;
    __syncthreads();
    if (tid == 0) {
        int bflat = (blockIdx.z * gridDim.y + blockIdx.y) * gridDim.x + blockIdx.x;
        pmax[bflat] = fmaxf(fmaxf(wred[0], wred[1]), fmaxf(wred[2], wred[3]));
    }
    for (int e = tid; e < 2048; e += 256)
        if (histS[e]) atomicAdd(&hist[p * 2048 + e], histS[e]);
}

// median passes 1..2: filter by prefix, histogram next bits
__global__ void K_medN(const float* __restrict__ sob, unsigned* __restrict__ hist,
                       const unsigned* __restrict__ prefix, unsigned himask,
                       int shift, unsigned binmask) {
    __shared__ unsigned sh[2048];
    int t = threadIdx.x;
    int p = blockIdx.y;
    for (int i = t; i < 2048; i += 256) sh[i] = 0;
    __syncthreads();
    unsigned pfx = prefix[p];
    int base = blockIdx.x * 4096;
    for (int r = 0; r < 16; r++) {
        int ij = base + r * 256 + t;
        unsigned b = __float_as_uint(sob[(size_t)p * HW + ij]);
        if ((b & himask) == pfx) atomicAdd(&sh[(b >> shift) & binmask], 1u);
    }
    __syncthreads();
    for (int i = t; i < 2048; i += 256)
        if (sh[i]) atomicAdd(&hist[p * 2048 + i], sh[i]);
}

__global__ void K_scan(unsigned* hist, unsigned* prefix, int* krem, int shift, int nbins) {
    __shared__ unsigned sums[256];
    int p = blockIdx.x;
    unsigned* hp = hist + p * 2048;
    int t = threadIdx.x;
    int per = nbins / 256;
    unsigned s = 0;
    for (int q = 0; q < per; q++) s += hp[t * per + q];
    sums[t] = s;
    __syncthreads();
    for (int off = 1; off < 256; off <<= 1) {
        unsigned v = (t >= off) ? sums[t - off] : 0u;
        __syncthreads();
        sums[t] += v;
        __syncthreads();
    }
    int k = krem[p];
    __syncthreads();
    unsigned base = (t == 0) ? 0u : sums[t - 1];
    if ((int)base <= k && k < (int)sums[t]) {
        int cum = (int)base;
        int b = t * per;
        for (int q = 0; q < per; q++) {
            int c = (int)hp[t * per + q];
            if (cum + c > k) { b = t * per + q; break; }
            cum += c;
        }
        prefix[p] |= ((unsigned)b) << shift;
        krem[p] = k - cum;
    }
    __syncthreads();
    for (int q = t; q < 2048; q += 256) hp[q] = 0;
}

__global__ void K_thresh(const unsigned* prefix, const float* sg1, const float* ew1,
                         const float* sg2, const float* ew2,
                         float* lowv, float* highv, float* wgtv) {
    int s = threadIdx.x;
    if (s < 2) {
        float med = 0.0f;
        for (int p = 0; p < PPS; p++) med += __uint_as_float(prefix[s * PPS + p]);
        med *= 0.125f;
        float sgin = (s == 0) ? sg1[0] : sg2[0];
        float ewin = (s == 0) ? ew1[0] : ew2[0];
        float sigm = 1.0f / (1.0f + expf(-sgin));
        float sig = 1.0f - sigm;
        lowv[s] = fminf(fmaxf((1.0f - sig) * med, 0.001f), 1.0f);
        highv[s] = fminf(fmaxf((1.0f + sig) * med, 0.001f), 1.0f);
        wgtv[s] = 1.0f / (1.0f + expf(-ewin));
    }
}

__global__ void K_redmax(const float* __restrict__ pmax, float* __restrict__ mx) {
    __shared__ float red[256];
    int t = threadIdx.x;
    for (int s = 0; s < 2; s++) {
        const float* base = pmax + s * (NBLK / 2);
        float v = -1e30f;
        for (int i = t; i < NBLK / 2; i += 256) v = fmaxf(v, base[i]);
        red[t] = v;
        __syncthreads();
        for (int sft = 128; sft > 0; sft >>= 1) {
            if (t < sft) red[t] = fmaxf(red[t], red[t + sft]);
            __syncthreads();
        }
        if (t == 0) mx[s] = red[0];
        __syncthreads();
    }
}

// hysteresis combine + dilation + sobel(original) blend, all tiles in LDS
__global__ void K_result(const float* __restrict__ sup, const float* __restrict__ im1,
                         const float* __restrict__ im2, const float* __restrict__ lowv,
                         const float* __restrict__ highv, const float* __restrict__ wgtv,
                         const float* __restrict__ mx, float* __restrict__ res,
                         float* __restrict__ prmax, float* __restrict__ prmin) {
    int p = blockIdx.z;
    int s = p >> 3;
    float m = mx[s];
    float inv = 1.0f / ((m > 0.0f) ? m : 1.0f);
    float lo = lowv[s], hi = highv[s], wg = wgtv[s];
    const float* sp = sup + (size_t)p * HW;
    const float* op = plane_ptr(im1, im2, p);
    int j0 = blockIdx.x * TX, i0 = blockIdx.y * TY;
    __shared__ float hs2[TY + 2][TX + 2];   // hsw(sup_norm - hi), zero outside image
    __shared__ float ssn[TY][TX];           // normalized sup, interior
    __shared__ float og[TY + 2][TX + 2];    // original image, zero outside
    __shared__ float wredx[4], wredn[4];
    int tid = threadIdx.y * 64 + threadIdx.x;

    for (int e = tid; e < (TY + 2) * (TX + 2); e += 256) {
        int y = e / (TX + 2), x = e % (TX + 2);
        int gi = i0 - 1 + y, gj = j0 - 1 + x;
        float h = 0.0f, o = 0.0f;
        if (gi >= 0 && gi < H && gj >= 0 && gj < W) {
            float sv = sp[gi * W + gj] * inv;
            h = hsw(sv - hi);
            o = op[gi * W + gj];
            if (y >= 1 && y <= TY && x >= 1 && x <= TX) ssn[y - 1][x - 1] = sv;
        }
        hs2[y][x] = h;
        og[y][x] = o;
    }
    __syncthreads();

    float bmx = -1e30f, bmn = 1e30f;
    for (int q = 0; q < TY / 4; q++) {
        int yl = threadIdx.y + q * 4;
        int xl = threadIdx.x;
        float sn0 = ssn[yl][xl];
        float Sh0 = hs2[yl + 1][xl + 1];
        float Sl0 = hsw(sn0 - lo);
        float dil = 0.0f;
        for (int a = 0; a < 3; a++)
            for (int b = 0; b < 3; b++) dil += hs2[yl + a][xl + b];
        float pre = sn0 * (Sh0 + Sl0) + dil * Sl0 * (1.0f - Sh0);

        float exo = (og[yl][xl + 2] - og[yl][xl]) + 2.0f * (og[yl + 1][xl + 2] - og[yl + 1][xl]) +
                    (og[yl + 2][xl + 2] - og[yl + 2][xl]);
        float eyo = (og[yl + 2][xl] + 2.0f * og[yl + 2][xl + 1] + og[yl + 2][xl + 2]) -
                    (og[yl][xl] + 2.0f * og[yl][xl + 1] + og[yl][xl + 2]);
        float sob = 0.5f * fabsf(exo) + 0.5f * fabsf(eyo);

        float r = (1.0f - wg) * pre + wg * sob;
        res[(size_t)p * HW + (i0 + yl) * W + (j0 + xl)] = r;
        bmx = fmaxf(bmx, r);
        bmn = fminf(bmn, r);
    }

    float vx = wave_max(bmx), vn = wave_min(bmn);
    if ((tid & 63) == 0) { wredx[tid >> 6] = vx; wredn[tid >> 6] = vn; }
    __syncthreads();
    if (tid == 0) {
        int bflat = (blockIdx.z * gridDim.y + blockIdx.y) * gridDim.x + blockIdx.x;
        prmax[bflat] = fmaxf(fmaxf(wredx[0], wredx[1]), fmaxf(wredx[2], wredx[3]));
        prmin[bflat] = fminf(fminf(wredn[0], wredn[1]), fminf(wredn[2], wredn[3]));
    }
}

__global__ void K_redminmax(const float* __restrict__ prmax, const float* __restrict__ prmin,
                            float* __restrict__ rmaxv, float* __restrict__ rminv) {
    __shared__ float rmx[256], rmn[256];
    int t = threadIdx.x;
    for (int s = 0; s < 2; s++) {
        const float* bx = prmax + s * (NBLK / 2);
        const float* bn = prmin + s * (NBLK / 2);
        float vx = -1e30f, vn = 1e30f;
        for (int i = t; i < NBLK / 2; i += 256) {
            vx = fmaxf(vx, bx[i]);
            vn = fminf(vn, bn[i]);
        }
        rmx[t] = vx;
        rmn[t] = vn;
        __syncthreads();
        for (int sft = 128; sft > 0; sft >>= 1) {
            if (t < sft) {
                rmx[t] = fmaxf(rmx[t], rmx[t + sft]);
                rmn[t] = fminf(rmn[t], rmn[t + sft]);
            }
            __syncthreads();
        }
        if (t == 0) { rmaxv[s] = rmx[0]; rminv[s] = rmn[0]; }
        __syncthreads();
    }
}

__global__ void K_final(const float* __restrict__ res, const float* __restrict__ rmaxv,
                        const float* __restrict__ rminv, float* __restrict__ out) {
    int j = blockIdx.x * 64 + threadIdx.x;
    int i = blockIdx.y * 4 + threadIdx.y;
    int p = blockIdx.z;  // 0..7
    float mx1 = rmaxv[0], mn1 = rminv[0];
    float mx2 = rmaxv[1], mn2 = rminv[1];
    size_t idx = (size_t)p * HW + i * W + j;
    float r1 = res[idx];
    float r2 = res[(size_t)(p + PPS) * HW + i * W + j];
    float m1 = (r1 - mn1) / (mx1 - mn1);
    float m2 = (r2 - mn2) / (mx2 - mn2);
    out[idx] = m1 + m2 - 2.0f * m1 * m2;               // 1 - f
    out[(size_t)PPS * HW + idx] = m1;
    out[(size_t)2 * PPS * HW + idx] = m2;
}

}  // namespace

extern "C" void kernel_launch(void* const* d_in, const int* in_sizes, int n_in,
                              void* d_out, int out_size, void* d_ws, size_t ws_size,
                              hipStream_t stream) {
    const float* img1 = (const float*)d_in[0];
    const float* img2 = (const float*)d_in[1];
    const float* sg1 = (const float*)d_in[2];
    const float* ew1 = (const float*)d_in[3];
    const float* sg2 = (const float*)d_in[4];
    const float* ew2 = (const float*)d_in[5];
    float* out = (float*)d_out;

    float* A = (float*)d_ws;                             // blurred
    float* B = A + (size_t)NP * HW;                      // sob, later res
    float* C = B + (size_t)NP * HW;                      // sup
    unsigned* hist = (unsigned*)(C + (size_t)NP * HW);   // NP*2048
    unsigned* prefix = hist + NP * 2048;
    int* krem = (int*)(prefix + NP);
    float* lowv = (float*)(krem + NP);
    float* highv = lowv + 2;
    float* wgtv = highv + 2;
    float* mx = wgtv + 2;
    float* rmaxv = mx + 2;
    float* rminv = rmaxv + 2;
    float* pmax = rminv + 2;           // NBLK
    float* prmax = pmax + NBLK;        // NBLK
    float* prmin = prmax + NBLK;       // NBLK

    dim3 blk(64, 4, 1);
    dim3 grdT(W / TX, H / TY, NP);       // dnms / result
    dim3 grdS(W / 64, H / S3_TY, NP);    // smooth3
    dim3 grdF(W / 64, H / 4, PPS);       // final
    dim3 mblk(256, 1, 1);
    dim3 mgrd(64, NP, 1);

    K_init<<<dim3(1), dim3(256), 0, stream>>>(hist, prefix, krem);

    // all 3 smoothing iterations fused: in -> A (blurred)
    K_smooth3<<<grdS, blk, 0, stream>>>(img1, img2, A);

    // fused derivs+NMS+sob+hist0: A -> sup(C), sob(B), hist, pmax
    K_dnms<<<grdT, blk, 0, stream>>>(A, C, B, hist, pmax);

    // median refinement (bits 20..10, 9..0) + thresholds
    K_scan<<<dim3(NP), mblk, 0, stream>>>(hist, prefix, krem, 21, 2048);
    K_medN<<<mgrd, mblk, 0, stream>>>(B, hist, prefix, 0xFFE00000u, 10, 2047u);
    K_scan<<<dim3(NP), mblk, 0, stream>>>(hist, prefix, krem, 10, 2048);
    K_medN<<<mgrd, mblk, 0, stream>>>(B, hist, prefix, 0xFFFFFC00u, 0, 1023u);
    K_scan<<<dim3(NP), mblk, 0, stream>>>(hist, prefix, krem, 0, 1024);
    K_thresh<<<dim3(1), dim3(64), 0, stream>>>(prefix, sg1, ew1, sg2, ew2, lowv, highv, wgtv);

    K_redmax<<<dim3(1), mblk, 0, stream>>>(pmax, mx);
    K_result<<<grdT, blk, 0, stream>>>(C, img1, img2, lowv, highv, wgtv, mx, B, prmax, prmin);
    K_redminmax<<<dim3(1), mblk, 0, stream>>>(prmax, prmin, rmaxv, rminv);
    K_final<<<grdF, blk, 0, stream>>>(B, rmaxv, rminv, out);
}

// Round 5
// 176.921 us; speedup vs baseline: 1.1827x; 1.1827x over previous
//
#include <hip/hip_runtime.h>

namespace {

constexpr int H = 512;
constexpr int W = 512;
constexpr int HW = H * W;
constexpr int PPS = 8;    // planes per canny set
constexpr int NP = 16;    // total planes (2 sets x 8)
constexpr int TX = 64;    // tile width
constexpr int TY = 8;     // tile height
constexpr int NBLK = (W / TX) * (H / TY) * NP;   // 8192
constexpr float PI_F = 3.14159265358979323846f;

__device__ __forceinline__ float hsw(float x) {
    float t = fminf(fmaxf(x + 3.0f, 0.0f), 6.0f);
    return x * t * (1.0f / 6.0f);
}

__device__ __forceinline__ const float* plane_ptr(const float* s1, const float* s2, int p) {
    return (p < PPS) ? (s1 + (size_t)p * HW) : (s2 + (size_t)(p - PPS) * HW);
}

__device__ __forceinline__ float wave_max(float v) {
    for (int o = 32; o > 0; o >>= 1) v = fmaxf(v, __shfl_down(v, o, 64));
    return v;
}
__device__ __forceinline__ float wave_min(float v) {
    for (int o = 32; o > 0; o >>= 1) v = fminf(v, __shfl_down(v, o, 64));
    return v;
}

// minimax atan on [0,1], err ~2e-7
__device__ __forceinline__ float atan_poly(float t) {
    float z = t * t;
    float p = -0.01172120f;
    p = p * z + 0.05265332f;
    p = p * z - 0.11643287f;
    p = p * z + 0.19354346f;
    p = p * z - 0.33262347f;
    p = p * z + 0.99997726f;
    return t * p;
}

__global__ void K_init(unsigned* hist, unsigned* prefix, int* krem) {
    int t = threadIdx.x;
    for (int i = t; i < NP * 2048; i += 256) hist[i] = 0;
    if (t < NP) { prefix[t] = 0; krem[t] = (HW - 1) / 2; }
}

// One full adaptive-smoothing iteration, fused (w in LDS, exact clip semantics).
__global__ void K_smooth(const float* __restrict__ s1, const float* __restrict__ s2,
                         float* __restrict__ fout) {
    int p = blockIdx.z;
    const float* f = plane_ptr(s1, s2, p);
    int j0 = blockIdx.x * TX, i0 = blockIdx.y * TY;
    __shared__ float fs[TY + 4][TX + 4];   // f[clip(i0-2+y)][clip(j0-2+x)]
    __shared__ float ws[TY + 2][TX + 2];   // w(clip(i0-1+y), clip(j0-1+x))
    int tid = threadIdx.y * 64 + threadIdx.x;

    for (int e = tid; e < (TY + 4) * (TX + 4); e += 256) {
        int y = e / (TX + 4), x = e % (TX + 4);
        int gi = min(max(i0 - 2 + y, 0), H - 1);
        int gj = min(max(j0 - 2 + x, 0), W - 1);
        fs[y][x] = f[gi * W + gj];
    }
    __syncthreads();

    for (int e = tid; e < (TY + 2) * (TX + 2); e += 256) {
        int y = e / (TX + 2), x = e % (TX + 2);
        int r = min(max(i0 - 1 + y, 0), H - 1);   // w evaluated at CLIPPED coords
        int c = min(max(j0 - 1 + x, 0), W - 1);
        int yf = r - (i0 - 2), xf = c - (j0 - 2);
        float gx = 0.5f * (fs[yf + 1][xf] - fs[yf - 1][xf]);
        float gy = 0.5f * (fs[yf][xf + 1] - fs[yf][xf - 1]);
        ws[y][x] = __expf(-(gx * gx + gy * gy) * (1.0f / 200.0f));
    }
    __syncthreads();

    for (int q = 0; q < TY / 4; q++) {
        int yl = threadIdx.y + q * 4;
        int xl = threadIdx.x;
        float num = 0.0f, den = 0.0f;
        for (int a = -1; a <= 1; a++) {
            for (int b = -1; b <= 1; b++) {
                float wv = ws[yl + 1 + a][xl + 1 + b];
                float fv = fs[yl + 2 + a][xl + 2 + b];
                num += fv * wv;
                den += wv;
            }
        }
        fout[(size_t)p * HW + (i0 + yl) * W + (j0 + xl)] = num / fmaxf(den, 1e-8f);
    }
}

// fused derivatives + NMS + sob write + median pass-0 histogram
__global__ void K_dnms(const float* __restrict__ blur, float* __restrict__ sup,
                       float* __restrict__ sob, unsigned* __restrict__ hist,
                       float* __restrict__ pmax) {
    int p = blockIdx.z;
    const float* f = blur + (size_t)p * HW;
    int j0 = blockIdx.x * TX, i0 = blockIdx.y * TY;
    __shared__ float fs[TY + 4][TX + 4];        // blur at clipped coords, halo 2
    __shared__ float ms[TY + 2][TX + 2];        // mag at clipped coords (replicate pad)
    __shared__ float exs[TY][TX], eys[TY][TX];  // interior zero-pad sobel components
    __shared__ unsigned histS[2048];
    __shared__ float wred[4];
    int tid = threadIdx.y * 64 + threadIdx.x;

    for (int e = tid; e < 2048; e += 256) histS[e] = 0;
    for (int e = tid; e < (TY + 4) * (TX + 4); e += 256) {
        int y = e / (TX + 4), x = e % (TX + 4);
        int gi = min(max(i0 - 2 + y, 0), H - 1);
        int gj = min(max(j0 - 2 + x, 0), W - 1);
        fs[y][x] = f[gi * W + gj];
    }
    __syncthreads();

    auto tap = [&](int rr, int cc) -> float {
        return (rr >= 0 && rr < H && cc >= 0 && cc < W) ? fs[rr - i0 + 2][cc - j0 + 2] : 0.0f;
    };

    for (int e = tid; e < (TY + 2) * (TX + 2); e += 256) {
        int y = e / (TX + 2), x = e % (TX + 2);
        int r = min(max(i0 - 1 + y, 0), H - 1);
        int c = min(max(j0 - 1 + x, 0), W - 1);
        float xmm = tap(r - 1, c - 1), xm0 = tap(r - 1, c), xmp = tap(r - 1, c + 1);
        float x0m = tap(r, c - 1), x0p = tap(r, c + 1);
        float xpm = tap(r + 1, c - 1), xp0 = tap(r + 1, c), xpp = tap(r + 1, c + 1);
        float ex = (xmp - xmm) + 2.0f * (x0p - x0m) + (xpp - xpm);
        float ey = (xpm + 2.0f * xp0 + xpp) - (xmm + 2.0f * xm0 + xmp);
        float e45 = -2.0f * xmm - xm0 - x0m + x0p + xp0 + 2.0f * xpp;
        float e135 = xm0 + 2.0f * xmp - x0m + x0p - 2.0f * xpm - xp0;
        ms[y][x] = sqrtf(ex * ex + ey * ey + e45 * e45 + e135 * e135);
        if (y >= 1 && y <= TY && x >= 1 && x <= TX) {
            exs[y - 1][x - 1] = ex;
            eys[y - 1][x - 1] = ey;
        }
    }
    __syncthreads();

    float bmax = 0.0f;
    for (int q = 0; q < TY / 4; q++) {
        int yl = threadIdx.y + q * 4;
        int xl = threadIdx.x;
        float ex = exs[yl][xl], ey = eys[yl][xl];

        // fast mod-pi line angle
        float ax = fabsf(ex), ay = fabsf(ey);
        float mn = fminf(ax, ay), mxv = fmaxf(ax, ay);
        float t = (mxv > 0.0f) ? __fdividef(mn, mxv) : 0.0f;
        float pang = atan_poly(t);
        if (ay > ax) pang = 1.57079632679f - pang;
        bool obtuse = ((__float_as_uint(ex) ^ __float_as_uint(ey)) & 0x80000000u) != 0u;
        float a = obtuse ? PI_F - pang : pang;

        // direction weights: softmax(-100*circdist) without max-sub (bounded)
        float d0 = fminf(a, PI_F - a);
        float t1 = fabsf(a - 0.78539816340f); float d1 = fminf(t1, PI_F - t1);
        float t2 = fabsf(a - 1.57079632679f); float d2 = fminf(t2, PI_F - t2);
        float t3 = fabsf(a - 2.35619449019f); float d3 = fminf(t3, PI_F - t3);
        float e0 = __expf(d0 * -100.0f), e1 = __expf(d1 * -100.0f);
        float e2 = __expf(d2 * -100.0f), e3 = __expf(d3 * -100.0f);
        float winv = __fdividef(1.0f, e0 + e1 + e2 + e3);

        float m0 = ms[yl + 1][xl + 1];
        float n1s[4] = {ms[yl + 1][xl], ms[yl][xl], ms[yl][xl + 1], ms[yl][xl + 2]};
        float n2s[4] = {ms[yl + 1][xl + 2], ms[yl + 2][xl + 2], ms[yl + 2][xl + 1], ms[yl + 2][xl]};
        float dws[4] = {e0, e1, e2, e3};

        float sAcc = 0.0f;
        for (int d = 0; d < 4; d++) {
            float g1 = __expf((n1s[d] - m0) * 10.0f);
            float g2 = __expf((n2s[d] - m0) * 10.0f);
            float sw = __fdividef(1.0f, 1.0f + g1 + g2);
            sAcc += sw * dws[d];
        }
        float s = m0 * sAcc * winv;
        size_t gidx = (size_t)p * HW + (i0 + yl) * W + (j0 + xl);
        sup[gidx] = s;
        bmax = fmaxf(bmax, s);

        // median pass 0: sob value + LDS histogram (top 11 bits)
        float sv = 0.5f * (ax + ay);
        sob[gidx] = sv;
        atomicAdd(&histS[__float_as_uint(sv) >> 21], 1u);
    }

    float wv = wave_max(bmax);
    if ((tid & 63) == 0) wred[tid >> 6] = wv;
    __syncthreads();
    if (tid == 0) {
        int bflat = (blockIdx.z * gridDim.y + blockIdx.y) * gridDim.x + blockIdx.x;
        pmax[bflat] = fmaxf(fmaxf(wred[0], wred[1]), fmaxf(wred[2], wred[3]));
    }
    for (int e = tid; e < 2048; e += 256)
        if (histS[e]) atomicAdd(&hist[p * 2048 + e], histS[e]);
}

// median passes 1..2: filter by prefix, histogram next bits
__global__ void K_medN(const float* __restrict__ sob, unsigned* __restrict__ hist,
                       const unsigned* __restrict__ prefix, unsigned himask,
                       int shift, unsigned binmask) {
    __shared__ unsigned sh[2048];
    int t = threadIdx.x;
    int p = blockIdx.y;
    for (int i = t; i < 2048; i += 256) sh[i] = 0;
    __syncthreads();
    unsigned pfx = prefix[p];
    int base = blockIdx.x * 4096;
    for (int r = 0; r < 16; r++) {
        int ij = base + r * 256 + t;
        unsigned b = __float_as_uint(sob[(size_t)p * HW + ij]);
        if ((b & himask) == pfx) atomicAdd(&sh[(b >> shift) & binmask], 1u);
    }
    __syncthreads();
    for (int i = t; i < 2048; i += 256)
        if (sh[i]) atomicAdd(&hist[p * 2048 + i], sh[i]);
}

__global__ void K_scan(unsigned* hist, unsigned* prefix, int* krem, int shift, int nbins) {
    __shared__ unsigned sums[256];
    int p = blockIdx.x;
    unsigned* hp = hist + p * 2048;
    int t = threadIdx.x;
    int per = nbins / 256;
    unsigned s = 0;
    for (int q = 0; q < per; q++) s += hp[t * per + q];
    sums[t] = s;
    __syncthreads();
    for (int off = 1; off < 256; off <<= 1) {
        unsigned v = (t >= off) ? sums[t - off] : 0u;
        __syncthreads();
        sums[t] += v;
        __syncthreads();
    }
    int k = krem[p];
    __syncthreads();
    unsigned base = (t == 0) ? 0u : sums[t - 1];
    if ((int)base <= k && k < (int)sums[t]) {
        int cum = (int)base;
        int b = t * per;
        for (int q = 0; q < per; q++) {
            int c = (int)hp[t * per + q];
            if (cum + c > k) { b = t * per + q; break; }
            cum += c;
        }
        prefix[p] |= ((unsigned)b) << shift;
        krem[p] = k - cum;
    }
    __syncthreads();
    for (int q = t; q < 2048; q += 256) hp[q] = 0;
}

__global__ void K_thresh(const unsigned* prefix, const float* sg1, const float* ew1,
                         const float* sg2, const float* ew2,
                         float* lowv, float* highv, float* wgtv) {
    int s = threadIdx.x;
    if (s < 2) {
        float med = 0.0f;
        for (int p = 0; p < PPS; p++) med += __uint_as_float(prefix[s * PPS + p]);
        med *= 0.125f;
        float sgin = (s == 0) ? sg1[0] : sg2[0];
        float ewin = (s == 0) ? ew1[0] : ew2[0];
        float sigm = 1.0f / (1.0f + expf(-sgin));
        float sig = 1.0f - sigm;
        lowv[s] = fminf(fmaxf((1.0f - sig) * med, 0.001f), 1.0f);
        highv[s] = fminf(fmaxf((1.0f + sig) * med, 0.001f), 1.0f);
        wgtv[s] = 1.0f / (1.0f + expf(-ewin));
    }
}

__global__ void K_redmax(const float* __restrict__ pmax, float* __restrict__ mx) {
    __shared__ float red[256];
    int t = threadIdx.x;
    for (int s = 0; s < 2; s++) {
        const float* base = pmax + s * (NBLK / 2);
        float v = -1e30f;
        for (int i = t; i < NBLK / 2; i += 256) v = fmaxf(v, base[i]);
        red[t] = v;
        __syncthreads();
        for (int sft = 128; sft > 0; sft >>= 1) {
            if (t < sft) red[t] = fmaxf(red[t], red[t + sft]);
            __syncthreads();
        }
        if (t == 0) mx[s] = red[0];
        __syncthreads();
    }
}

// hysteresis combine + dilation + sobel(original) blend, all tiles in LDS
__global__ void K_result(const float* __restrict__ sup, const float* __restrict__ im1,
                         const float* __restrict__ im2, const float* __restrict__ lowv,
                         const float* __restrict__ highv, const float* __restrict__ wgtv,
                         const float* __restrict__ mx, float* __restrict__ res,
                         float* __restrict__ prmax, float* __restrict__ prmin) {
    int p = blockIdx.z;
    int s = p >> 3;
    float m = mx[s];
    float inv = 1.0f / ((m > 0.0f) ? m : 1.0f);
    float lo = lowv[s], hi = highv[s], wg = wgtv[s];
    const float* sp = sup + (size_t)p * HW;
    const float* op = plane_ptr(im1, im2, p);
    int j0 = blockIdx.x * TX, i0 = blockIdx.y * TY;
    __shared__ float hs2[TY + 2][TX + 2];   // hsw(sup_norm - hi), zero outside image
    __shared__ float ssn[TY][TX];           // normalized sup, interior
    __shared__ float og[TY + 2][TX + 2];    // original image, zero outside
    __shared__ float wredx[4], wredn[4];
    int tid = threadIdx.y * 64 + threadIdx.x;

    for (int e = tid; e < (TY + 2) * (TX + 2); e += 256) {
        int y = e / (TX + 2), x = e % (TX + 2);
        int gi = i0 - 1 + y, gj = j0 - 1 + x;
        float h = 0.0f, o = 0.0f;
        if (gi >= 0 && gi < H && gj >= 0 && gj < W) {
            float sv = sp[gi * W + gj] * inv;
            h = hsw(sv - hi);
            o = op[gi * W + gj];
            if (y >= 1 && y <= TY && x >= 1 && x <= TX) ssn[y - 1][x - 1] = sv;
        }
        hs2[y][x] = h;
        og[y][x] = o;
    }
    __syncthreads();

    float bmx = -1e30f, bmn = 1e30f;
    for (int q = 0; q < TY / 4; q++) {
        int yl = threadIdx.y + q * 4;
        int xl = threadIdx.x;
        float sn0 = ssn[yl][xl];
        float Sh0 = hs2[yl + 1][xl + 1];
        float Sl0 = hsw(sn0 - lo);
        float dil = 0.0f;
        for (int a = 0; a < 3; a++)
            for (int b = 0; b < 3; b++) dil += hs2[yl + a][xl + b];
        float pre = sn0 * (Sh0 + Sl0) + dil * Sl0 * (1.0f - Sh0);

        float exo = (og[yl][xl + 2] - og[yl][xl]) + 2.0f * (og[yl + 1][xl + 2] - og[yl + 1][xl]) +
                    (og[yl + 2][xl + 2] - og[yl + 2][xl]);
        float eyo = (og[yl + 2][xl] + 2.0f * og[yl + 2][xl + 1] + og[yl + 2][xl + 2]) -
                    (og[yl][xl] + 2.0f * og[yl][xl + 1] + og[yl][xl + 2]);
        float sob = 0.5f * fabsf(exo) + 0.5f * fabsf(eyo);

        float r = (1.0f - wg) * pre + wg * sob;
        res[(size_t)p * HW + (i0 + yl) * W + (j0 + xl)] = r;
        bmx = fmaxf(bmx, r);
        bmn = fminf(bmn, r);
    }

    float vx = wave_max(bmx), vn = wave_min(bmn);
    if ((tid & 63) == 0) { wredx[tid >> 6] = vx; wredn[tid >> 6] = vn; }
    __syncthreads();
    if (tid == 0) {
        int bflat = (blockIdx.z * gridDim.y + blockIdx.y) * gridDim.x + blockIdx.x;
        prmax[bflat] = fmaxf(fmaxf(wredx[0], wredx[1]), fmaxf(wredx[2], wredx[3]));
        prmin[bflat] = fminf(fminf(wredn[0], wredn[1]), fminf(wredn[2], wredn[3]));
    }
}

__global__ void K_redminmax(const float* __restrict__ prmax, const float* __restrict__ prmin,
                            float* __restrict__ rmaxv, float* __restrict__ rminv) {
    __shared__ float rmx[256], rmn[256];
    int t = threadIdx.x;
    for (int s = 0; s < 2; s++) {
        const float* bx = prmax + s * (NBLK / 2);
        const float* bn = prmin + s * (NBLK / 2);
        float vx = -1e30f, vn = 1e30f;
        for (int i = t; i < NBLK / 2; i += 256) {
            vx = fmaxf(vx, bx[i]);
            vn = fminf(vn, bn[i]);
        }
        rmx[t] = vx;
        rmn[t] = vn;
        __syncthreads();
        for (int sft = 128; sft > 0; sft >>= 1) {
            if (t < sft) {
                rmx[t] = fmaxf(rmx[t], rmx[t + sft]);
                rmn[t] = fminf(rmn[t], rmn[t + sft]);
            }
            __syncthreads();
        }
        if (t == 0) { rmaxv[s] = rmx[0]; rminv[s] = rmn[0]; }
        __syncthreads();
    }
}

__global__ void K_final(const float* __restrict__ res, const float* __restrict__ rmaxv,
                        const float* __restrict__ rminv, float* __restrict__ out) {
    int j = blockIdx.x * 64 + threadIdx.x;
    int i = blockIdx.y * 4 + threadIdx.y;
    int p = blockIdx.z;  // 0..7
    float mx1 = rmaxv[0], mn1 = rminv[0];
    float mx2 = rmaxv[1], mn2 = rminv[1];
    size_t idx = (size_t)p * HW + i * W + j;
    float r1 = res[idx];
    float r2 = res[(size_t)(p + PPS) * HW + i * W + j];
    float m1 = (r1 - mn1) / (mx1 - mn1);
    float m2 = (r2 - mn2) / (mx2 - mn2);
    out[idx] = m1 + m2 - 2.0f * m1 * m2;               // 1 - f
    out[(size_t)PPS * HW + idx] = m1;
    out[(size_t)2 * PPS * HW + idx] = m2;
}

}  // namespace

extern "C" void kernel_launch(void* const* d_in, const int* in_sizes, int n_in,
                              void* d_out, int out_size, void* d_ws, size_t ws_size,
                              hipStream_t stream) {
    const float* img1 = (const float*)d_in[0];
    const float* img2 = (const float*)d_in[1];
    const float* sg1 = (const float*)d_in[2];
    const float* ew1 = (const float*)d_in[3];
    const float* sg2 = (const float*)d_in[4];
    const float* ew2 = (const float*)d_in[5];
    float* out = (float*)d_out;

    float* A = (float*)d_ws;                             // ping / blurred
    float* B = A + (size_t)NP * HW;                      // pong / sob / res
    float* C = B + (size_t)NP * HW;                      // sup
    unsigned* hist = (unsigned*)(C + (size_t)NP * HW);   // NP*2048
    unsigned* prefix = hist + NP * 2048;
    int* krem = (int*)(prefix + NP);
    float* lowv = (float*)(krem + NP);
    float* highv = lowv + 2;
    float* wgtv = highv + 2;
    float* mx = wgtv + 2;
    float* rmaxv = mx + 2;
    float* rminv = rmaxv + 2;
    float* pmax = rminv + 2;           // NBLK
    float* prmax = pmax + NBLK;        // NBLK
    float* prmin = prmax + NBLK;       // NBLK

    dim3 blk(64, 4, 1);
    dim3 grdT(W / TX, H / TY, NP);     // tiled kernels
    dim3 grdF(W / 64, H / 4, PPS);     // final
    dim3 mblk(256, 1, 1);
    dim3 mgrd(64, NP, 1);

    K_init<<<dim3(1), dim3(256), 0, stream>>>(hist, prefix, krem);

    // adaptive smoothing: 3 fused iterations  in->A, A->B, B->A  (blurred -> A)
    K_smooth<<<grdT, blk, 0, stream>>>(img1, img2, A);
    K_smooth<<<grdT, blk, 0, stream>>>(A, A + (size_t)PPS * HW, B);
    K_smooth<<<grdT, blk, 0, stream>>>(B, B + (size_t)PPS * HW, A);

    // fused derivs+NMS+sob+hist0: A -> sup(C), sob(B), hist, pmax
    K_dnms<<<grdT, blk, 0, stream>>>(A, C, B, hist, pmax);

    // median refinement (bits 20..10, 9..0) + thresholds
    K_scan<<<dim3(NP), mblk, 0, stream>>>(hist, prefix, krem, 21, 2048);
    K_medN<<<mgrd, mblk, 0, stream>>>(B, hist, prefix, 0xFFE00000u, 10, 2047u);
    K_scan<<<dim3(NP), mblk, 0, stream>>>(hist, prefix, krem, 10, 2048);
    K_medN<<<mgrd, mblk, 0, stream>>>(B, hist, prefix, 0xFFFFFC00u, 0, 1023u);
    K_scan<<<dim3(NP), mblk, 0, stream>>>(hist, prefix, krem, 0, 1024);
    K_thresh<<<dim3(1), dim3(64), 0, stream>>>(prefix, sg1, ew1, sg2, ew2, lowv, highv, wgtv);

    K_redmax<<<dim3(1), mblk, 0, stream>>>(pmax, mx);
    K_result<<<grdT, blk, 0, stream>>>(C, img1, img2, lowv, highv, wgtv, mx, B, prmax, prmin);
    K_redminmax<<<dim3(1), mblk, 0, stream>>>(prmax, prmin, rmaxv, rminv);
    K_final<<<grdF, blk, 0, stream>>>(B, rmaxv, rminv, out);
}

// Round 6
// 162.825 us; speedup vs baseline: 1.2851x; 1.0866x over previous
//
#include <hip/hip_runtime.h>

namespace {

constexpr int H = 512;
constexpr int W = 512;
constexpr int HW = H * W;
constexpr int PPS = 8;    // planes per canny set
constexpr int NP = 16;    // total planes (2 sets x 8)
constexpr int TX = 64;    // tile width
constexpr int TY = 8;     // tile height
constexpr int NBLK = (W / TX) * (H / TY) * NP;   // 8192
constexpr float PI_F = 3.14159265358979323846f;
constexpr int NBINS = 2048;                 // fixed-point median bins over [0,4)
constexpr float BIN_SCALE = 512.0f;         // bin = sv * 512

__device__ __forceinline__ float hsw(float x) {
    float t = fminf(fmaxf(x + 3.0f, 0.0f), 6.0f);
    return x * t * (1.0f / 6.0f);
}

__device__ __forceinline__ const float* plane_ptr(const float* s1, const float* s2, int p) {
    return (p < PPS) ? (s1 + (size_t)p * HW) : (s2 + (size_t)(p - PPS) * HW);
}

__device__ __forceinline__ float wave_max(float v) {
    for (int o = 32; o > 0; o >>= 1) v = fmaxf(v, __shfl_down(v, o, 64));
    return v;
}
__device__ __forceinline__ float wave_min(float v) {
    for (int o = 32; o > 0; o >>= 1) v = fminf(v, __shfl_down(v, o, 64));
    return v;
}

// minimax atan on [0,1], err ~2e-7
__device__ __forceinline__ float atan_poly(float t) {
    float z = t * t;
    float p = -0.01172120f;
    p = p * z + 0.05265332f;
    p = p * z - 0.11643287f;
    p = p * z + 0.19354346f;
    p = p * z - 0.33262347f;
    p = p * z + 0.99997726f;
    return t * p;
}

__global__ void K_init(unsigned* hist) {
    int t = blockIdx.x * 256 + threadIdx.x;
    for (int i = t; i < NP * NBINS; i += gridDim.x * 256) hist[i] = 0;
}

// One full adaptive-smoothing iteration, fused (w in LDS, exact clip semantics).
// Each thread produces 2 ADJACENT rows -> shares 2 of 4 LDS rows between pixels.
__global__ void K_smooth(const float* __restrict__ s1, const float* __restrict__ s2,
                         float* __restrict__ fout) {
    int p = blockIdx.z;
    const float* f = plane_ptr(s1, s2, p);
    int j0 = blockIdx.x * TX, i0 = blockIdx.y * TY;
    __shared__ float fs[TY + 4][TX + 4];   // f[clip(i0-2+y)][clip(j0-2+x)]
    __shared__ float ws[TY + 2][TX + 2];   // w(clip(i0-1+y), clip(j0-1+x))
    int tid = threadIdx.y * 64 + threadIdx.x;

    for (int e = tid; e < (TY + 4) * (TX + 4); e += 256) {
        int y = e / (TX + 4), x = e % (TX + 4);
        int gi = min(max(i0 - 2 + y, 0), H - 1);
        int gj = min(max(j0 - 2 + x, 0), W - 1);
        fs[y][x] = f[gi * W + gj];
    }
    __syncthreads();

    for (int e = tid; e < (TY + 2) * (TX + 2); e += 256) {
        int y = e / (TX + 2), x = e % (TX + 2);
        int r = min(max(i0 - 1 + y, 0), H - 1);   // w evaluated at CLIPPED coords
        int c = min(max(j0 - 1 + x, 0), W - 1);
        int yf = r - (i0 - 2), xf = c - (j0 - 2);
        float gx = 0.5f * (fs[yf + 1][xf] - fs[yf - 1][xf]);
        float gy = 0.5f * (fs[yf][xf + 1] - fs[yf][xf - 1]);
        ws[y][x] = __expf(-(gx * gx + gy * gy) * (1.0f / 200.0f));
    }
    __syncthreads();

    int yl = threadIdx.y * 2;
    int xl = threadIdx.x;
    // w rows yl..yl+3, cols xl..xl+2 ; f rows yl+1..yl+4, cols xl+1..xl+3
    float w00 = ws[yl + 0][xl], w01 = ws[yl + 0][xl + 1], w02 = ws[yl + 0][xl + 2];
    float w10 = ws[yl + 1][xl], w11 = ws[yl + 1][xl + 1], w12 = ws[yl + 1][xl + 2];
    float w20 = ws[yl + 2][xl], w21 = ws[yl + 2][xl + 1], w22 = ws[yl + 2][xl + 2];
    float w30 = ws[yl + 3][xl], w31 = ws[yl + 3][xl + 1], w32 = ws[yl + 3][xl + 2];
    float f00 = fs[yl + 1][xl + 1], f01 = fs[yl + 1][xl + 2], f02 = fs[yl + 1][xl + 3];
    float f10 = fs[yl + 2][xl + 1], f11 = fs[yl + 2][xl + 2], f12 = fs[yl + 2][xl + 3];
    float f20 = fs[yl + 3][xl + 1], f21 = fs[yl + 3][xl + 2], f22 = fs[yl + 3][xl + 3];
    float f30 = fs[yl + 4][xl + 1], f31 = fs[yl + 4][xl + 2], f32 = fs[yl + 4][xl + 3];

    float rn0 = f00 * w00 + f01 * w01 + f02 * w02, rd0 = w00 + w01 + w02;
    float rn1 = f10 * w10 + f11 * w11 + f12 * w12, rd1 = w10 + w11 + w12;
    float rn2 = f20 * w20 + f21 * w21 + f22 * w22, rd2 = w20 + w21 + w22;
    float rn3 = f30 * w30 + f31 * w31 + f32 * w32, rd3 = w30 + w31 + w32;

    size_t base = (size_t)p * HW + (i0 + yl) * W + (j0 + xl);
    fout[base] = (rn0 + rn1 + rn2) / fmaxf(rd0 + rd1 + rd2, 1e-8f);
    fout[base + W] = (rn1 + rn2 + rn3) / fmaxf(rd1 + rd2 + rd3, 1e-8f);
}

// fused derivatives + NMS + fixed-point median histogram
__global__ void K_dnms(const float* __restrict__ blur, float* __restrict__ sup,
                       unsigned* __restrict__ hist, float* __restrict__ pmax) {
    int p = blockIdx.z;
    const float* f = blur + (size_t)p * HW;
    int j0 = blockIdx.x * TX, i0 = blockIdx.y * TY;
    __shared__ float fs[TY + 4][TX + 4];        // blur at clipped coords, halo 2
    __shared__ float ms[TY + 2][TX + 2];        // mag at clipped coords (replicate pad)
    __shared__ float exs[TY][TX], eys[TY][TX];  // interior zero-pad sobel components
    __shared__ unsigned histS[NBINS];
    __shared__ float wred[4];
    int tid = threadIdx.y * 64 + threadIdx.x;

    for (int e = tid; e < NBINS; e += 256) histS[e] = 0;
    for (int e = tid; e < (TY + 4) * (TX + 4); e += 256) {
        int y = e / (TX + 4), x = e % (TX + 4);
        int gi = min(max(i0 - 2 + y, 0), H - 1);
        int gj = min(max(j0 - 2 + x, 0), W - 1);
        fs[y][x] = f[gi * W + gj];
    }
    __syncthreads();

    auto tap = [&](int rr, int cc) -> float {
        return (rr >= 0 && rr < H && cc >= 0 && cc < W) ? fs[rr - i0 + 2][cc - j0 + 2] : 0.0f;
    };

    for (int e = tid; e < (TY + 2) * (TX + 2); e += 256) {
        int y = e / (TX + 2), x = e % (TX + 2);
        int r = min(max(i0 - 1 + y, 0), H - 1);
        int c = min(max(j0 - 1 + x, 0), W - 1);
        float xmm = tap(r - 1, c - 1), xm0 = tap(r - 1, c), xmp = tap(r - 1, c + 1);
        float x0m = tap(r, c - 1), x0p = tap(r, c + 1);
        float xpm = tap(r + 1, c - 1), xp0 = tap(r + 1, c), xpp = tap(r + 1, c + 1);
        float ex = (xmp - xmm) + 2.0f * (x0p - x0m) + (xpp - xpm);
        float ey = (xpm + 2.0f * xp0 + xpp) - (xmm + 2.0f * xm0 + xmp);
        float e45 = -2.0f * xmm - xm0 - x0m + x0p + xp0 + 2.0f * xpp;
        float e135 = xm0 + 2.0f * xmp - x0m + x0p - 2.0f * xpm - xp0;
        ms[y][x] = sqrtf(ex * ex + ey * ey + e45 * e45 + e135 * e135);
        if (y >= 1 && y <= TY && x >= 1 && x <= TX) {
            exs[y - 1][x - 1] = ex;
            eys[y - 1][x - 1] = ey;
        }
    }
    __syncthreads();

    float bmax = 0.0f;
    for (int q = 0; q < TY / 4; q++) {
        int yl = threadIdx.y + q * 4;
        int xl = threadIdx.x;
        float ex = exs[yl][xl], ey = eys[yl][xl];

        // fast mod-pi line angle
        float ax = fabsf(ex), ay = fabsf(ey);
        float mn = fminf(ax, ay), mxv = fmaxf(ax, ay);
        float t = (mxv > 0.0f) ? __fdividef(mn, mxv) : 0.0f;
        float pang = atan_poly(t);
        if (ay > ax) pang = 1.57079632679f - pang;
        bool obtuse = ((__float_as_uint(ex) ^ __float_as_uint(ey)) & 0x80000000u) != 0u;
        float a = obtuse ? PI_F - pang : pang;

        // direction weights: softmax(-100*circdist) without max-sub (bounded)
        float d0 = fminf(a, PI_F - a);
        float t1 = fabsf(a - 0.78539816340f); float d1 = fminf(t1, PI_F - t1);
        float t2 = fabsf(a - 1.57079632679f); float d2 = fminf(t2, PI_F - t2);
        float t3 = fabsf(a - 2.35619449019f); float d3 = fminf(t3, PI_F - t3);
        float e0 = __expf(d0 * -100.0f), e1 = __expf(d1 * -100.0f);
        float e2 = __expf(d2 * -100.0f), e3 = __expf(d3 * -100.0f);
        float winv = __fdividef(1.0f, e0 + e1 + e2 + e3);

        float m0 = ms[yl + 1][xl + 1];
        float n1s[4] = {ms[yl + 1][xl], ms[yl][xl], ms[yl][xl + 1], ms[yl][xl + 2]};
        float n2s[4] = {ms[yl + 1][xl + 2], ms[yl + 2][xl + 2], ms[yl + 2][xl + 1], ms[yl + 2][xl]};
        float dws[4] = {e0, e1, e2, e3};

        float sAcc = 0.0f;
        for (int d = 0; d < 4; d++) {
            float g1 = __expf((n1s[d] - m0) * 10.0f);
            float g2 = __expf((n2s[d] - m0) * 10.0f);
            float sw = __fdividef(1.0f, 1.0f + g1 + g2);
            sAcc += sw * dws[d];
        }
        float s = m0 * sAcc * winv;
        sup[(size_t)p * HW + (i0 + yl) * W + (j0 + xl)] = s;
        bmax = fmaxf(bmax, s);

        // median histogram: sob quantized to 2048 bins over [0,4)
        float sv = 0.5f * (ax + ay);
        int bin = min((int)(sv * BIN_SCALE), NBINS - 1);
        atomicAdd(&histS[bin], 1u);
    }

    float wv = wave_max(bmax);
    if ((tid & 63) == 0) wred[tid >> 6] = wv;
    __syncthreads();
    if (tid == 0) {
        int bflat = (blockIdx.z * gridDim.y + blockIdx.y) * gridDim.x + blockIdx.x;
        pmax[bflat] = fmaxf(fmaxf(wred[0], wred[1]), fmaxf(wred[2], wred[3]));
    }
    for (int e = tid; e < NBINS; e += 256)
        if (histS[e]) atomicAdd(&hist[p * NBINS + e], histS[e]);
}

// per-plane: find lower-median bin from the histogram -> medv[p]
__global__ void K_medpick(const unsigned* __restrict__ hist, float* __restrict__ medv) {
    __shared__ unsigned sums[256];
    int p = blockIdx.x;
    const unsigned* hp = hist + p * NBINS;
    int t = threadIdx.x;
    unsigned s = 0;
    for (int q = 0; q < NBINS / 256; q++) s += hp[t * (NBINS / 256) + q];
    sums[t] = s;
    __syncthreads();
    for (int off = 1; off < 256; off <<= 1) {
        unsigned v = (t >= off) ? sums[t - off] : 0u;
        __syncthreads();
        sums[t] += v;
        __syncthreads();
    }
    const int k = (HW - 1) / 2;
    unsigned base = (t == 0) ? 0u : sums[t - 1];
    if ((int)base <= k && k < (int)sums[t]) {
        int cum = (int)base;
        int b = t * (NBINS / 256);
        for (int q = 0; q < NBINS / 256; q++) {
            int c = (int)hp[t * (NBINS / 256) + q];
            if (cum + c > k) { b = t * (NBINS / 256) + q; break; }
            cum += c;
        }
        medv[p] = ((float)b + 0.5f) * (1.0f / BIN_SCALE);
    }
}

__global__ void K_thresh(const float* medv, const float* sg1, const float* ew1,
                         const float* sg2, const float* ew2,
                         float* lowv, float* highv, float* wgtv) {
    int s = threadIdx.x;
    if (s < 2) {
        float med = 0.0f;
        for (int p = 0; p < PPS; p++) med += medv[s * PPS + p];
        med *= 0.125f;
        float sgin = (s == 0) ? sg1[0] : sg2[0];
        float ewin = (s == 0) ? ew1[0] : ew2[0];
        float sigm = 1.0f / (1.0f + expf(-sgin));
        float sig = 1.0f - sigm;
        lowv[s] = fminf(fmaxf((1.0f - sig) * med, 0.001f), 1.0f);
        highv[s] = fminf(fmaxf((1.0f + sig) * med, 0.001f), 1.0f);
        wgtv[s] = 1.0f / (1.0f + expf(-ewin));
    }
}

__global__ void K_redmax(const float* __restrict__ pmax, float* __restrict__ mx) {
    __shared__ float red[256];
    int t = threadIdx.x;
    for (int s = 0; s < 2; s++) {
        const float* base = pmax + s * (NBLK / 2);
        float v = -1e30f;
        for (int i = t; i < NBLK / 2; i += 256) v = fmaxf(v, base[i]);
        red[t] = v;
        __syncthreads();
        for (int sft = 128; sft > 0; sft >>= 1) {
            if (t < sft) red[t] = fmaxf(red[t], red[t + sft]);
            __syncthreads();
        }
        if (t == 0) mx[s] = red[0];
        __syncthreads();
    }
}

// hysteresis combine + dilation + sobel(original) blend; 2 adjacent rows/thread
__global__ void K_result(const float* __restrict__ sup, const float* __restrict__ im1,
                         const float* __restrict__ im2, const float* __restrict__ lowv,
                         const float* __restrict__ highv, const float* __restrict__ wgtv,
                         const float* __restrict__ mx, float* __restrict__ res,
                         float* __restrict__ prmax, float* __restrict__ prmin) {
    int p = blockIdx.z;
    int s = p >> 3;
    float m = mx[s];
    float inv = 1.0f / ((m > 0.0f) ? m : 1.0f);
    float lo = lowv[s], hi = highv[s], wg = wgtv[s];
    const float* sp = sup + (size_t)p * HW;
    const float* op = plane_ptr(im1, im2, p);
    int j0 = blockIdx.x * TX, i0 = blockIdx.y * TY;
    __shared__ float hs2[TY + 2][TX + 2];   // hsw(sup_norm - hi), zero outside image
    __shared__ float ssn[TY][TX];           // normalized sup, interior
    __shared__ float og[TY + 2][TX + 2];    // original image, zero outside
    __shared__ float wredx[4], wredn[4];
    int tid = threadIdx.y * 64 + threadIdx.x;

    for (int e = tid; e < (TY + 2) * (TX + 2); e += 256) {
        int y = e / (TX + 2), x = e % (TX + 2);
        int gi = i0 - 1 + y, gj = j0 - 1 + x;
        float h = 0.0f, o = 0.0f;
        if (gi >= 0 && gi < H && gj >= 0 && gj < W) {
            float sv = sp[gi * W + gj] * inv;
            h = hsw(sv - hi);
            o = op[gi * W + gj];
            if (y >= 1 && y <= TY && x >= 1 && x <= TX) ssn[y - 1][x - 1] = sv;
        }
        hs2[y][x] = h;
        og[y][x] = o;
    }
    __syncthreads();

    int yl = threadIdx.y * 2;
    int xl = threadIdx.x;
    // h row sums (rows yl..yl+3, cols xl..xl+2)
    float h0 = hs2[yl + 0][xl] + hs2[yl + 0][xl + 1] + hs2[yl + 0][xl + 2];
    float h1 = hs2[yl + 1][xl] + hs2[yl + 1][xl + 1] + hs2[yl + 1][xl + 2];
    float h2 = hs2[yl + 2][xl] + hs2[yl + 2][xl + 1] + hs2[yl + 2][xl + 2];
    float h3 = hs2[yl + 3][xl] + hs2[yl + 3][xl + 1] + hs2[yl + 3][xl + 2];
    float Sh0 = hs2[yl + 1][xl + 1];
    float Sh1 = hs2[yl + 2][xl + 1];
    float sn0 = ssn[yl][xl], sn1 = ssn[yl + 1][xl];

    // original-image sobel pieces (rows yl..yl+3)
    float oa0 = og[yl + 0][xl], ob0 = og[yl + 0][xl + 1], oc0 = og[yl + 0][xl + 2];
    float oa1 = og[yl + 1][xl], ob1 = og[yl + 1][xl + 1], oc1 = og[yl + 1][xl + 2];
    float oa2 = og[yl + 2][xl], ob2 = og[yl + 2][xl + 1], oc2 = og[yl + 2][xl + 2];
    float oa3 = og[yl + 3][xl], ob3 = og[yl + 3][xl + 1], oc3 = og[yl + 3][xl + 2];
    float dd0 = oc0 - oa0, dd1 = oc1 - oa1, dd2 = oc2 - oa2, dd3 = oc3 - oa3;
    float ss0 = oa0 + 2.0f * ob0 + oc0, ss1 = oa1 + 2.0f * ob1 + oc1;
    float ss2 = oa2 + 2.0f * ob2 + oc2, ss3 = oa3 + 2.0f * ob3 + oc3;

    float Sl0 = hsw(sn0 - lo);
    float Sl1 = hsw(sn1 - lo);
    float pre0 = sn0 * (Sh0 + Sl0) + (h0 + h1 + h2) * Sl0 * (1.0f - Sh0);
    float pre1 = sn1 * (Sh1 + Sl1) + (h1 + h2 + h3) * Sl1 * (1.0f - Sh1);
    float sob0 = 0.5f * fabsf(dd0 + 2.0f * dd1 + dd2) + 0.5f * fabsf(ss2 - ss0);
    float sob1 = 0.5f * fabsf(dd1 + 2.0f * dd2 + dd3) + 0.5f * fabsf(ss3 - ss1);

    float r0 = (1.0f - wg) * pre0 + wg * sob0;
    float r1 = (1.0f - wg) * pre1 + wg * sob1;
    size_t gbase = (size_t)p * HW + (i0 + yl) * W + (j0 + xl);
    res[gbase] = r0;
    res[gbase + W] = r1;
    float bmx = fmaxf(r0, r1), bmn = fminf(r0, r1);

    float vx = wave_max(bmx), vn = wave_min(bmn);
    if ((tid & 63) == 0) { wredx[tid >> 6] = vx; wredn[tid >> 6] = vn; }
    __syncthreads();
    if (tid == 0) {
        int bflat = (blockIdx.z * gridDim.y + blockIdx.y) * gridDim.x + blockIdx.x;
        prmax[bflat] = fmaxf(fmaxf(wredx[0], wredx[1]), fmaxf(wredx[2], wredx[3]));
        prmin[bflat] = fminf(fminf(wredn[0], wredn[1]), fminf(wredn[2], wredn[3]));
    }
}

__global__ void K_redminmax(const float* __restrict__ prmax, const float* __restrict__ prmin,
                            float* __restrict__ rmaxv, float* __restrict__ rminv) {
    __shared__ float rmx[256], rmn[256];
    int t = threadIdx.x;
    for (int s = 0; s < 2; s++) {
        const float* bx = prmax + s * (NBLK / 2);
        const float* bn = prmin + s * (NBLK / 2);
        float vx = -1e30f, vn = 1e30f;
        for (int i = t; i < NBLK / 2; i += 256) {
            vx = fmaxf(vx, bx[i]);
            vn = fminf(vn, bn[i]);
        }
        rmx[t] = vx;
        rmn[t] = vn;
        __syncthreads();
        for (int sft = 128; sft > 0; sft >>= 1) {
            if (t < sft) {
                rmx[t] = fmaxf(rmx[t], rmx[t + sft]);
                rmn[t] = fminf(rmn[t], rmn[t + sft]);
            }
            __syncthreads();
        }
        if (t == 0) { rmaxv[s] = rmx[0]; rminv[s] = rmn[0]; }
        __syncthreads();
    }
}

__global__ void K_final(const float* __restrict__ res, const float* __restrict__ rmaxv,
                        const float* __restrict__ rminv, float* __restrict__ out) {
    int j = blockIdx.x * 64 + threadIdx.x;
    int i = blockIdx.y * 4 + threadIdx.y;
    int p = blockIdx.z;  // 0..7
    float mx1 = rmaxv[0], mn1 = rminv[0];
    float mx2 = rmaxv[1], mn2 = rminv[1];
    size_t idx = (size_t)p * HW + i * W + j;
    float r1 = res[idx];
    float r2 = res[(size_t)(p + PPS) * HW + i * W + j];
    float m1 = (r1 - mn1) / (mx1 - mn1);
    float m2 = (r2 - mn2) / (mx2 - mn2);
    out[idx] = m1 + m2 - 2.0f * m1 * m2;               // 1 - f
    out[(size_t)PPS * HW + idx] = m1;
    out[(size_t)2 * PPS * HW + idx] = m2;
}

}  // namespace

extern "C" void kernel_launch(void* const* d_in, const int* in_sizes, int n_in,
                              void* d_out, int out_size, void* d_ws, size_t ws_size,
                              hipStream_t stream) {
    const float* img1 = (const float*)d_in[0];
    const float* img2 = (const float*)d_in[1];
    const float* sg1 = (const float*)d_in[2];
    const float* ew1 = (const float*)d_in[3];
    const float* sg2 = (const float*)d_in[4];
    const float* ew2 = (const float*)d_in[5];
    float* out = (float*)d_out;

    float* A = (float*)d_ws;                             // ping / blurred
    float* B = A + (size_t)NP * HW;                      // pong / res
    float* C = B + (size_t)NP * HW;                      // sup
    unsigned* hist = (unsigned*)(C + (size_t)NP * HW);   // NP*NBINS
    float* medv = (float*)(hist + NP * NBINS);           // 16
    float* lowv = medv + NP;
    float* highv = lowv + 2;
    float* wgtv = highv + 2;
    float* mx = wgtv + 2;
    float* rmaxv = mx + 2;
    float* rminv = rmaxv + 2;
    float* pmax = rminv + 2;           // NBLK
    float* prmax = pmax + NBLK;        // NBLK
    float* prmin = prmax + NBLK;       // NBLK

    dim3 blk(64, 4, 1);
    dim3 grdT(W / TX, H / TY, NP);     // tiled kernels
    dim3 grdF(W / 64, H / 4, PPS);     // final
    dim3 mblk(256, 1, 1);

    K_init<<<dim3(16), mblk, 0, stream>>>(hist);

    // adaptive smoothing: 3 iterations  in->A, A->B, B->A  (blurred -> A)
    K_smooth<<<grdT, blk, 0, stream>>>(img1, img2, A);
    K_smooth<<<grdT, blk, 0, stream>>>(A, A + (size_t)PPS * HW, B);
    K_smooth<<<grdT, blk, 0, stream>>>(B, B + (size_t)PPS * HW, A);

    // fused derivs+NMS+median-hist: A -> sup(C), hist, pmax
    K_dnms<<<grdT, blk, 0, stream>>>(A, C, hist, pmax);

    // median pick + thresholds
    K_medpick<<<dim3(NP), mblk, 0, stream>>>(hist, medv);
    K_thresh<<<dim3(1), dim3(64), 0, stream>>>(medv, sg1, ew1, sg2, ew2, lowv, highv, wgtv);

    K_redmax<<<dim3(1), mblk, 0, stream>>>(pmax, mx);
    K_result<<<grdT, blk, 0, stream>>>(C, img1, img2, lowv, highv, wgtv, mx, B, prmax, prmin);
    K_redminmax<<<dim3(1), mblk, 0, stream>>>(prmax, prmin, rmaxv, rminv);
    K_final<<<grdF, blk, 0, stream>>>(B, rmaxv, rminv, out);
}

// Round 7
// 154.319 us; speedup vs baseline: 1.3559x; 1.0551x over previous
//
#include <hip/hip_runtime.h>

namespace {

constexpr int H = 512;
constexpr int W = 512;
constexpr int HW = H * W;
constexpr int PPS = 8;    // planes per canny set
constexpr int NP = 16;    // total planes (2 sets x 8)
constexpr int TX = 64;    // tile width (dnms/result)
constexpr int TY = 8;     // tile height (dnms/result)
constexpr int STY = 16;   // smooth tile height (4 rows/thread)
constexpr int NBLK = (W / TX) * (H / TY) * NP;   // 8192
constexpr float PI_F = 3.14159265358979323846f;
constexpr int NBINS = 1024;                 // median bins over [0,2)
constexpr float BIN_SCALE = 512.0f;

__device__ __forceinline__ float hsw(float x) {
    float t = fminf(fmaxf(x + 3.0f, 0.0f), 6.0f);
    return x * t * (1.0f / 6.0f);
}

__device__ __forceinline__ const float* plane_ptr(const float* s1, const float* s2, int p) {
    return (p < PPS) ? (s1 + (size_t)p * HW) : (s2 + (size_t)(p - PPS) * HW);
}

__device__ __forceinline__ float wave_max(float v) {
    for (int o = 32; o > 0; o >>= 1) v = fmaxf(v, __shfl_down(v, o, 64));
    return v;
}
__device__ __forceinline__ float wave_min(float v) {
    for (int o = 32; o > 0; o >>= 1) v = fminf(v, __shfl_down(v, o, 64));
    return v;
}

// minimax atan on [0,1], err ~2e-7
__device__ __forceinline__ float atan_poly(float t) {
    float z = t * t;
    float p = -0.01172120f;
    p = p * z + 0.05265332f;
    p = p * z - 0.11643287f;
    p = p * z + 0.19354346f;
    p = p * z - 0.33262347f;
    p = p * z + 0.99997726f;
    return t * p;
}

// 4-to-1 mux with static code (no runtime-indexed arrays)
__device__ __forceinline__ float sel4(int idx, float v0, float v1, float v2, float v3) {
    float a = (idx & 1) ? v1 : v0;
    float b = (idx & 1) ? v3 : v2;
    return (idx & 2) ? b : a;
}

__global__ void K_init(unsigned* hist) {
    int t = blockIdx.x * 256 + threadIdx.x;
    for (int i = t; i < NP * NBINS; i += gridDim.x * 256) hist[i] = 0;
}

// One adaptive-smoothing iteration; 16-row tile, 4 adjacent rows per thread.
__global__ void K_smooth(const float* __restrict__ s1, const float* __restrict__ s2,
                         float* __restrict__ fout) {
    int p = blockIdx.z;
    const float* f = plane_ptr(s1, s2, p);
    int j0 = blockIdx.x * 64, i0 = blockIdx.y * STY;
    __shared__ float fs[STY + 4][68];   // f[clip(i0-2+y)][clip(j0-2+x)]
    __shared__ float ws[STY + 2][66];   // w(clip(i0-1+y), clip(j0-1+x))
    int tid = threadIdx.y * 64 + threadIdx.x;

    for (int e = tid; e < (STY + 4) * 68; e += 256) {
        int y = e / 68, x = e % 68;
        int gi = min(max(i0 - 2 + y, 0), H - 1);
        int gj = min(max(j0 - 2 + x, 0), W - 1);
        fs[y][x] = f[gi * W + gj];
    }
    __syncthreads();

    for (int e = tid; e < (STY + 2) * 66; e += 256) {
        int y = e / 66, x = e % 66;
        int r = min(max(i0 - 1 + y, 0), H - 1);   // w evaluated at CLIPPED coords
        int c = min(max(j0 - 1 + x, 0), W - 1);
        int yr = r - (i0 - 2), xc = c - (j0 - 2);
        int ym = max(r - 1, 0) - (i0 - 2), yp = min(r + 1, H - 1) - (i0 - 2);
        int xm = max(c - 1, 0) - (j0 - 2), xp = min(c + 1, W - 1) - (j0 - 2);
        float gx = 0.5f * (fs[yp][xc] - fs[ym][xc]);
        float gy = 0.5f * (fs[yr][xp] - fs[yr][xm]);
        ws[y][x] = __expf(-(gx * gx + gy * gy) * (1.0f / 200.0f));
    }
    __syncthreads();

    int yl = threadIdx.y * 4;
    int xl = threadIdx.x;
    float rn[6], rd[6];
#pragma unroll
    for (int k = 0; k < 6; k++) {
        float w0 = ws[yl + k][xl], w1 = ws[yl + k][xl + 1], w2 = ws[yl + k][xl + 2];
        float fA = fs[yl + k + 1][xl + 1], fB = fs[yl + k + 1][xl + 2], fC = fs[yl + k + 1][xl + 3];
        rn[k] = fA * w0 + fB * w1 + fC * w2;
        rd[k] = w0 + w1 + w2;
    }
    size_t base = (size_t)p * HW + (i0 + yl) * W + (j0 + xl);
#pragma unroll
    for (int k = 0; k < 4; k++) {
        fout[base + (size_t)k * W] =
            (rn[k] + rn[k + 1] + rn[k + 2]) / fmaxf(rd[k] + rd[k + 1] + rd[k + 2], 1e-8f);
    }
}

// fused derivatives + NMS (2-direction softmax) + median histogram
__global__ void K_dnms(const float* __restrict__ blur, float* __restrict__ sup,
                       unsigned* __restrict__ hist, float* __restrict__ pmax) {
    int p = blockIdx.z;
    const float* f = blur + (size_t)p * HW;
    int j0 = blockIdx.x * TX, i0 = blockIdx.y * TY;
    __shared__ float fs0[TY + 4][TX + 4];       // ZERO-padded blur at absolute coords
    __shared__ float ms[TY + 2][TX + 2];        // mag at clipped coords
    __shared__ float exs[TY][TX], eys[TY][TX];  // interior sobel components
    __shared__ unsigned histS[NBINS];
    __shared__ float wred[4];
    int tid = threadIdx.y * 64 + threadIdx.x;

    for (int e = tid; e < NBINS; e += 256) histS[e] = 0;
    for (int e = tid; e < (TY + 4) * (TX + 4); e += 256) {
        int y = e / (TX + 4), x = e % (TX + 4);
        int gi = i0 - 2 + y, gj = j0 - 2 + x;
        fs0[y][x] = (gi >= 0 && gi < H && gj >= 0 && gj < W) ? f[gi * W + gj] : 0.0f;
    }
    __syncthreads();

    for (int e = tid; e < (TY + 2) * (TX + 2); e += 256) {
        int y = e / (TX + 2), x = e % (TX + 2);
        int r = min(max(i0 - 1 + y, 0), H - 1);
        int c = min(max(j0 - 1 + x, 0), W - 1);
        int rr = r - i0 + 2, cc = c - j0 + 2;   // fs0 is zero-padded: taps unconditional
        float xmm = fs0[rr - 1][cc - 1], xm0 = fs0[rr - 1][cc], xmp = fs0[rr - 1][cc + 1];
        float x0m = fs0[rr][cc - 1], x0p = fs0[rr][cc + 1];
        float xpm = fs0[rr + 1][cc - 1], xp0 = fs0[rr + 1][cc], xpp = fs0[rr + 1][cc + 1];
        float ex = (xmp - xmm) + 2.0f * (x0p - x0m) + (xpp - xpm);
        float ey = (xpm + 2.0f * xp0 + xpp) - (xmm + 2.0f * xm0 + xmp);
        float e45 = -2.0f * xmm - xm0 - x0m + x0p + xp0 + 2.0f * xpp;
        float e135 = xm0 + 2.0f * xmp - x0m + x0p - 2.0f * xpm - xp0;
        ms[y][x] = sqrtf(ex * ex + ey * ey + e45 * e45 + e135 * e135);
        if (y >= 1 && y <= TY && x >= 1 && x <= TX) {
            exs[y - 1][x - 1] = ex;
            eys[y - 1][x - 1] = ey;
        }
    }
    __syncthreads();

    float bmax = 0.0f;
    for (int q = 0; q < TY / 4; q++) {
        int yl = threadIdx.y + q * 4;
        int xl = threadIdx.x;
        float ex = exs[yl][xl], ey = eys[yl][xl];

        // fast mod-pi line angle
        float ax = fabsf(ex), ay = fabsf(ey);
        float mn = fminf(ax, ay), mxv = fmaxf(ax, ay);
        float tq = (mxv > 0.0f) ? __fdividef(mn, mxv) : 0.0f;
        float pang = atan_poly(tq);
        if (ay > ax) pang = 1.57079632679f - pang;
        bool obtuse = ((__float_as_uint(ex) ^ __float_as_uint(ey)) & 0x80000000u) != 0u;
        float a = obtuse ? PI_F - pang : pang;

        // nearest + second-nearest direction; other two weigh <= e^(-25*pi)
        float fa = a * 1.27323954474f;          // a * 4/pi  in [0,4]
        float nf = floorf(fa + 0.5f);           // 0..4
        float diff = a - nf * 0.78539816340f;
        float delta = fabsf(diff);
        int n = (int)nf & 3;
        int m = ((diff >= 0.0f) ? (int)nf + 1 : (int)nf - 1) & 3;
        float t = __expf(200.0f * delta - 78.5398163397f);   // e^{-100(pi/4-2delta)} <= 1
        float u = __fdividef(1.0f, 1.0f + t);

        float m0 = ms[yl + 1][xl + 1];
        float n1a = ms[yl + 1][xl], n1b = ms[yl][xl], n1c = ms[yl][xl + 1], n1d = ms[yl][xl + 2];
        float n2a = ms[yl + 1][xl + 2], n2b = ms[yl + 2][xl + 2], n2c = ms[yl + 2][xl + 1], n2d = ms[yl + 2][xl];
        float n1n = sel4(n, n1a, n1b, n1c, n1d);
        float n2n = sel4(n, n2a, n2b, n2c, n2d);
        float n1m = sel4(m, n1a, n1b, n1c, n1d);
        float n2m = sel4(m, n2a, n2b, n2c, n2d);

        float g1n = __expf((n1n - m0) * 10.0f);
        float g2n = __expf((n2n - m0) * 10.0f);
        float g1m = __expf((n1m - m0) * 10.0f);
        float g2m = __expf((n2m - m0) * 10.0f);
        float swn = __fdividef(1.0f, 1.0f + g1n + g2n);
        float swm = __fdividef(1.0f, 1.0f + g1m + g2m);
        float s = m0 * u * (swn + t * swm);

        sup[(size_t)p * HW + (i0 + yl) * W + (j0 + xl)] = s;
        bmax = fmaxf(bmax, s);

        // median histogram: sob quantized, bins over [0,2)
        float sv = 0.5f * (ax + ay);
        int bin = min((int)(sv * BIN_SCALE), NBINS - 1);
        atomicAdd(&histS[bin], 1u);
    }

    float wv = wave_max(bmax);
    if ((tid & 63) == 0) wred[tid >> 6] = wv;
    __syncthreads();
    if (tid == 0) {
        int bflat = (blockIdx.z * gridDim.y + blockIdx.y) * gridDim.x + blockIdx.x;
        pmax[bflat] = fmaxf(fmaxf(wred[0], wred[1]), fmaxf(wred[2], wred[3]));
    }
    for (int e = tid; e < NBINS; e += 256)
        if (histS[e]) atomicAdd(&hist[p * NBINS + e], histS[e]);
}

// per-plane: find lower-median bin from the histogram -> medv[p]
__global__ void K_medpick(const unsigned* __restrict__ hist, float* __restrict__ medv) {
    __shared__ unsigned sums[256];
    int p = blockIdx.x;
    const unsigned* hp = hist + p * NBINS;
    int t = threadIdx.x;
    unsigned s = 0;
    for (int q = 0; q < NBINS / 256; q++) s += hp[t * (NBINS / 256) + q];
    sums[t] = s;
    __syncthreads();
    for (int off = 1; off < 256; off <<= 1) {
        unsigned v = (t >= off) ? sums[t - off] : 0u;
        __syncthreads();
        sums[t] += v;
        __syncthreads();
    }
    const int k = (HW - 1) / 2;
    unsigned base = (t == 0) ? 0u : sums[t - 1];
    if ((int)base <= k && k < (int)sums[t]) {
        int cum = (int)base;
        int b = t * (NBINS / 256);
        for (int q = 0; q < NBINS / 256; q++) {
            int c = (int)hp[t * (NBINS / 256) + q];
            if (cum + c > k) { b = t * (NBINS / 256) + q; break; }
            cum += c;
        }
        medv[p] = ((float)b + 0.5f) * (1.0f / BIN_SCALE);
    }
}

__global__ void K_thresh(const float* medv, const float* sg1, const float* ew1,
                         const float* sg2, const float* ew2,
                         float* lowv, float* highv, float* wgtv) {
    int s = threadIdx.x;
    if (s < 2) {
        float med = 0.0f;
        for (int p = 0; p < PPS; p++) med += medv[s * PPS + p];
        med *= 0.125f;
        float sgin = (s == 0) ? sg1[0] : sg2[0];
        float ewin = (s == 0) ? ew1[0] : ew2[0];
        float sigm = 1.0f / (1.0f + expf(-sgin));
        float sig = 1.0f - sigm;
        lowv[s] = fminf(fmaxf((1.0f - sig) * med, 0.001f), 1.0f);
        highv[s] = fminf(fmaxf((1.0f + sig) * med, 0.001f), 1.0f);
        wgtv[s] = 1.0f / (1.0f + expf(-ewin));
    }
}

__global__ void K_redmax(const float* __restrict__ pmax, float* __restrict__ mx) {
    __shared__ float red[256];
    int t = threadIdx.x;
    for (int s = 0; s < 2; s++) {
        const float* base = pmax + s * (NBLK / 2);
        float v = -1e30f;
        for (int i = t; i < NBLK / 2; i += 256) v = fmaxf(v, base[i]);
        red[t] = v;
        __syncthreads();
        for (int sft = 128; sft > 0; sft >>= 1) {
            if (t < sft) red[t] = fmaxf(red[t], red[t + sft]);
            __syncthreads();
        }
        if (t == 0) mx[s] = red[0];
        __syncthreads();
    }
}

// hysteresis combine + dilation + sobel(original) blend; 2 adjacent rows/thread
__global__ void K_result(const float* __restrict__ sup, const float* __restrict__ im1,
                         const float* __restrict__ im2, const float* __restrict__ lowv,
                         const float* __restrict__ highv, const float* __restrict__ wgtv,
                         const float* __restrict__ mx, float* __restrict__ res,
                         float* __restrict__ prmax, float* __restrict__ prmin) {
    int p = blockIdx.z;
    int s = p >> 3;
    float m = mx[s];
    float inv = 1.0f / ((m > 0.0f) ? m : 1.0f);
    float lo = lowv[s], hi = highv[s], wg = wgtv[s];
    const float* sp = sup + (size_t)p * HW;
    const float* op = plane_ptr(im1, im2, p);
    int j0 = blockIdx.x * TX, i0 = blockIdx.y * TY;
    __shared__ float hs2[TY + 2][TX + 2];   // hsw(sup_norm - hi), zero outside image
    __shared__ float ssn[TY][TX];           // normalized sup, interior
    __shared__ float og[TY + 2][TX + 2];    // original image, zero outside
    __shared__ float wredx[4], wredn[4];
    int tid = threadIdx.y * 64 + threadIdx.x;

    for (int e = tid; e < (TY + 2) * (TX + 2); e += 256) {
        int y = e / (TX + 2), x = e % (TX + 2);
        int gi = i0 - 1 + y, gj = j0 - 1 + x;
        float h = 0.0f, o = 0.0f;
        if (gi >= 0 && gi < H && gj >= 0 && gj < W) {
            float sv = sp[gi * W + gj] * inv;
            h = hsw(sv - hi);
            o = op[gi * W + gj];
            if (y >= 1 && y <= TY && x >= 1 && x <= TX) ssn[y - 1][x - 1] = sv;
        }
        hs2[y][x] = h;
        og[y][x] = o;
    }
    __syncthreads();

    int yl = threadIdx.y * 2;
    int xl = threadIdx.x;
    float h0 = hs2[yl + 0][xl] + hs2[yl + 0][xl + 1] + hs2[yl + 0][xl + 2];
    float h1 = hs2[yl + 1][xl] + hs2[yl + 1][xl + 1] + hs2[yl + 1][xl + 2];
    float h2 = hs2[yl + 2][xl] + hs2[yl + 2][xl + 1] + hs2[yl + 2][xl + 2];
    float h3 = hs2[yl + 3][xl] + hs2[yl + 3][xl + 1] + hs2[yl + 3][xl + 2];
    float Sh0 = hs2[yl + 1][xl + 1];
    float Sh1 = hs2[yl + 2][xl + 1];
    float sn0 = ssn[yl][xl], sn1 = ssn[yl + 1][xl];

    float oa0 = og[yl + 0][xl], ob0 = og[yl + 0][xl + 1], oc0 = og[yl + 0][xl + 2];
    float oa1 = og[yl + 1][xl], ob1 = og[yl + 1][xl + 1], oc1 = og[yl + 1][xl + 2];
    float oa2 = og[yl + 2][xl], ob2 = og[yl + 2][xl + 1], oc2 = og[yl + 2][xl + 2];
    float oa3 = og[yl + 3][xl], ob3 = og[yl + 3][xl + 1], oc3 = og[yl + 3][xl + 2];
    float dd0 = oc0 - oa0, dd1 = oc1 - oa1, dd2 = oc2 - oa2, dd3 = oc3 - oa3;
    float ss0 = oa0 + 2.0f * ob0 + oc0, ss1 = oa1 + 2.0f * ob1 + oc1;
    float ss2 = oa2 + 2.0f * ob2 + oc2, ss3 = oa3 + 2.0f * ob3 + oc3;

    float Sl0 = hsw(sn0 - lo);
    float Sl1 = hsw(sn1 - lo);
    float pre0 = sn0 * (Sh0 + Sl0) + (h0 + h1 + h2) * Sl0 * (1.0f - Sh0);
    float pre1 = sn1 * (Sh1 + Sl1) + (h1 + h2 + h3) * Sl1 * (1.0f - Sh1);
    float sob0 = 0.5f * fabsf(dd0 + 2.0f * dd1 + dd2) + 0.5f * fabsf(ss2 - ss0);
    float sob1 = 0.5f * fabsf(dd1 + 2.0f * dd2 + dd3) + 0.5f * fabsf(ss3 - ss1);

    float r0 = (1.0f - wg) * pre0 + wg * sob0;
    float r1 = (1.0f - wg) * pre1 + wg * sob1;
    size_t gbase = (size_t)p * HW + (i0 + yl) * W + (j0 + xl);
    res[gbase] = r0;
    res[gbase + W] = r1;
    float bmx = fmaxf(r0, r1), bmn = fminf(r0, r1);

    float vx = wave_max(bmx), vn = wave_min(bmn);
    if ((tid & 63) == 0) { wredx[tid >> 6] = vx; wredn[tid >> 6] = vn; }
    __syncthreads();
    if (tid == 0) {
        int bflat = (blockIdx.z * gridDim.y + blockIdx.y) * gridDim.x + blockIdx.x;
        prmax[bflat] = fmaxf(fmaxf(wredx[0], wredx[1]), fmaxf(wredx[2], wredx[3]));
        prmin[bflat] = fminf(fminf(wredn[0], wredn[1]), fminf(wredn[2], wredn[3]));
    }
}

__global__ void K_redminmax(const float* __restrict__ prmax, const float* __restrict__ prmin,
                            float* __restrict__ rmaxv, float* __restrict__ rminv) {
    __shared__ float rmx[256], rmn[256];
    int t = threadIdx.x;
    for (int s = 0; s < 2; s++) {
        const float* bx = prmax + s * (NBLK / 2);
        const float* bn = prmin + s * (NBLK / 2);
        float vx = -1e30f, vn = 1e30f;
        for (int i = t; i < NBLK / 2; i += 256) {
            vx = fmaxf(vx, bx[i]);
            vn = fminf(vn, bn[i]);
        }
        rmx[t] = vx;
        rmn[t] = vn;
        __syncthreads();
        for (int sft = 128; sft > 0; sft >>= 1) {
            if (t < sft) {
                rmx[t] = fmaxf(rmx[t], rmx[t + sft]);
                rmn[t] = fminf(rmn[t], rmn[t + sft]);
            }
            __syncthreads();
        }
        if (t == 0) { rmaxv[s] = rmx[0]; rminv[s] = rmn[0]; }
        __syncthreads();
    }
}

__global__ void K_final(const float* __restrict__ res, const float* __restrict__ rmaxv,
                        const float* __restrict__ rminv, float* __restrict__ out) {
    int j = blockIdx.x * 64 + threadIdx.x;
    int i = blockIdx.y * 4 + threadIdx.y;
    int p = blockIdx.z;  // 0..7
    float mx1 = rmaxv[0], mn1 = rminv[0];
    float mx2 = rmaxv[1], mn2 = rminv[1];
    size_t idx = (size_t)p * HW + i * W + j;
    float r1 = res[idx];
    float r2 = res[(size_t)(p + PPS) * HW + i * W + j];
    float m1 = (r1 - mn1) / (mx1 - mn1);
    float m2 = (r2 - mn2) / (mx2 - mn2);
    out[idx] = m1 + m2 - 2.0f * m1 * m2;               // 1 - f
    out[(size_t)PPS * HW + idx] = m1;
    out[(size_t)2 * PPS * HW + idx] = m2;
}

}  // namespace

extern "C" void kernel_launch(void* const* d_in, const int* in_sizes, int n_in,
                              void* d_out, int out_size, void* d_ws, size_t ws_size,
                              hipStream_t stream) {
    const float* img1 = (const float*)d_in[0];
    const float* img2 = (const float*)d_in[1];
    const float* sg1 = (const float*)d_in[2];
    const float* ew1 = (const float*)d_in[3];
    const float* sg2 = (const float*)d_in[4];
    const float* ew2 = (const float*)d_in[5];
    float* out = (float*)d_out;

    float* A = (float*)d_ws;                             // ping / blurred
    float* B = A + (size_t)NP * HW;                      // pong / res
    float* C = B + (size_t)NP * HW;                      // sup
    unsigned* hist = (unsigned*)(C + (size_t)NP * HW);   // NP*NBINS
    float* medv = (float*)(hist + NP * NBINS);           // 16
    float* lowv = medv + NP;
    float* highv = lowv + 2;
    float* wgtv = highv + 2;
    float* mx = wgtv + 2;
    float* rmaxv = mx + 2;
    float* rminv = rmaxv + 2;
    float* pmax = rminv + 2;           // NBLK
    float* prmax = pmax + NBLK;        // NBLK
    float* prmin = prmax + NBLK;       // NBLK

    dim3 blk(64, 4, 1);
    dim3 grdT(W / TX, H / TY, NP);     // dnms / result
    dim3 grdS(W / 64, H / STY, NP);    // smooth
    dim3 grdF(W / 64, H / 4, PPS);     // final
    dim3 mblk(256, 1, 1);

    K_init<<<dim3(16), mblk, 0, stream>>>(hist);

    // adaptive smoothing: 3 iterations  in->A, A->B, B->A  (blurred -> A)
    K_smooth<<<grdS, blk, 0, stream>>>(img1, img2, A);
    K_smooth<<<grdS, blk, 0, stream>>>(A, A + (size_t)PPS * HW, B);
    K_smooth<<<grdS, blk, 0, stream>>>(B, B + (size_t)PPS * HW, A);

    // fused derivs+NMS+median-hist: A -> sup(C), hist, pmax
    K_dnms<<<grdT, blk, 0, stream>>>(A, C, hist, pmax);

    // median pick + thresholds
    K_medpick<<<dim3(NP), mblk, 0, stream>>>(hist, medv);
    K_thresh<<<dim3(1), dim3(64), 0, stream>>>(medv, sg1, ew1, sg2, ew2, lowv, highv, wgtv);

    K_redmax<<<dim3(1), mblk, 0, stream>>>(pmax, mx);
    K_result<<<grdT, blk, 0, stream>>>(C, img1, img2, lowv, highv, wgtv, mx, B, prmax, prmin);
    K_redminmax<<<dim3(1), mblk, 0, stream>>>(prmax, prmin, rmaxv, rminv);
    K_final<<<grdF, blk, 0, stream>>>(B, rmaxv, rminv, out);
}

// Round 8
// 130.371 us; speedup vs baseline: 1.6050x; 1.1837x over previous
//
#include <hip/hip_runtime.h>

namespace {

constexpr int H = 512;
constexpr int W = 512;
constexpr int HW = H * W;
constexpr int PPS = 8;    // planes per canny set
constexpr int NP = 16;    // total planes (2 sets x 8)
constexpr int TX = 64;    // tile width (dnms/result)
constexpr int TY = 16;    // tile height (dnms/result): 4 adjacent rows/thread
constexpr int STY = 16;   // smooth tile height
constexpr int NBLK = (W / TX) * (H / TY) * NP;   // 4096
constexpr float PI_F = 3.14159265358979323846f;
constexpr int NBINS = 1024;                 // median bins over [0,2)
constexpr float BIN_SCALE = 512.0f;

__device__ __forceinline__ float hsw(float x) {
    float t = fminf(fmaxf(x + 3.0f, 0.0f), 6.0f);
    return x * t * (1.0f / 6.0f);
}

__device__ __forceinline__ const float* plane_ptr(const float* s1, const float* s2, int p) {
    return (p < PPS) ? (s1 + (size_t)p * HW) : (s2 + (size_t)(p - PPS) * HW);
}

__device__ __forceinline__ float wave_max(float v) {
    for (int o = 32; o > 0; o >>= 1) v = fmaxf(v, __shfl_down(v, o, 64));
    return v;
}
__device__ __forceinline__ float wave_min(float v) {
    for (int o = 32; o > 0; o >>= 1) v = fminf(v, __shfl_down(v, o, 64));
    return v;
}

// minimax atan on [0,1], err ~2e-7
__device__ __forceinline__ float atan_poly(float t) {
    float z = t * t;
    float p = -0.01172120f;
    p = p * z + 0.05265332f;
    p = p * z - 0.11643287f;
    p = p * z + 0.19354346f;
    p = p * z - 0.33262347f;
    p = p * z + 0.99997726f;
    return t * p;
}

// 4-to-1 mux with static code (no runtime-indexed arrays)
__device__ __forceinline__ float sel4(int idx, float v0, float v1, float v2, float v3) {
    float a = (idx & 1) ? v1 : v0;
    float b = (idx & 1) ? v3 : v2;
    return (idx & 2) ? b : a;
}

__global__ void K_init(unsigned* hist) {
    int t = blockIdx.x * 256 + threadIdx.x;
    for (int i = t; i < NP * NBINS; i += gridDim.x * 256) hist[i] = 0;
}

// One adaptive-smoothing iteration; 16-row tile, 4 adjacent rows per thread.
__global__ void K_smooth(const float* __restrict__ s1, const float* __restrict__ s2,
                         float* __restrict__ fout) {
    int p = blockIdx.z;
    const float* f = plane_ptr(s1, s2, p);
    int j0 = blockIdx.x * 64, i0 = blockIdx.y * STY;
    __shared__ float fs[STY + 4][68];   // f[clip(i0-2+y)][clip(j0-2+x)]
    __shared__ float ws[STY + 2][66];   // w(clip(i0-1+y), clip(j0-1+x))
    int tid = threadIdx.y * 64 + threadIdx.x;

    for (int e = tid; e < (STY + 4) * 68; e += 256) {
        int y = e / 68, x = e % 68;
        int gi = min(max(i0 - 2 + y, 0), H - 1);
        int gj = min(max(j0 - 2 + x, 0), W - 1);
        fs[y][x] = f[gi * W + gj];
    }
    __syncthreads();

    for (int e = tid; e < (STY + 2) * 66; e += 256) {
        int y = e / 66, x = e % 66;
        int r = min(max(i0 - 1 + y, 0), H - 1);   // w evaluated at CLIPPED coords
        int c = min(max(j0 - 1 + x, 0), W - 1);
        int yr = r - (i0 - 2), xc = c - (j0 - 2);
        int ym = max(r - 1, 0) - (i0 - 2), yp = min(r + 1, H - 1) - (i0 - 2);
        int xm = max(c - 1, 0) - (j0 - 2), xp = min(c + 1, W - 1) - (j0 - 2);
        float gx = 0.5f * (fs[yp][xc] - fs[ym][xc]);
        float gy = 0.5f * (fs[yr][xp] - fs[yr][xm]);
        ws[y][x] = __expf(-(gx * gx + gy * gy) * (1.0f / 200.0f));
    }
    __syncthreads();

    int yl = threadIdx.y * 4;
    int xl = threadIdx.x;
    float rn[6], rd[6];
#pragma unroll
    for (int k = 0; k < 6; k++) {
        float w0 = ws[yl + k][xl], w1 = ws[yl + k][xl + 1], w2 = ws[yl + k][xl + 2];
        float fA = fs[yl + k + 1][xl + 1], fB = fs[yl + k + 1][xl + 2], fC = fs[yl + k + 1][xl + 3];
        rn[k] = fA * w0 + fB * w1 + fC * w2;
        rd[k] = w0 + w1 + w2;
    }
    size_t base = (size_t)p * HW + (i0 + yl) * W + (j0 + xl);
#pragma unroll
    for (int k = 0; k < 4; k++) {
        fout[base + (size_t)k * W] =
            (rn[k] + rn[k + 1] + rn[k + 2]) / fmaxf(rd[k] + rd[k + 1] + rd[k + 2], 1e-8f);
    }
}

// fused derivatives + NMS (2-direction softmax) + median histogram
__global__ void K_dnms(const float* __restrict__ blur, float* __restrict__ sup,
                       unsigned* __restrict__ hist, float* __restrict__ pmax) {
    int p = blockIdx.z;
    const float* f = blur + (size_t)p * HW;
    int j0 = blockIdx.x * TX, i0 = blockIdx.y * TY;
    __shared__ float fs0[TY + 4][TX + 4];       // ZERO-padded blur at absolute coords
    __shared__ float ms[TY + 2][TX + 2];        // mag at clipped coords
    __shared__ float exs[TY][TX], eys[TY][TX];  // interior sobel components
    __shared__ unsigned histS[NBINS];
    __shared__ float wred[4];
    int tid = threadIdx.y * 64 + threadIdx.x;

    for (int e = tid; e < NBINS; e += 256) histS[e] = 0;
    for (int e = tid; e < (TY + 4) * (TX + 4); e += 256) {
        int y = e / (TX + 4), x = e % (TX + 4);
        int gi = i0 - 2 + y, gj = j0 - 2 + x;
        fs0[y][x] = (gi >= 0 && gi < H && gj >= 0 && gj < W) ? f[gi * W + gj] : 0.0f;
    }
    __syncthreads();

    for (int e = tid; e < (TY + 2) * (TX + 2); e += 256) {
        int y = e / (TX + 2), x = e % (TX + 2);
        int r = min(max(i0 - 1 + y, 0), H - 1);
        int c = min(max(j0 - 1 + x, 0), W - 1);
        int rr = r - i0 + 2, cc = c - j0 + 2;   // fs0 is zero-padded: taps unconditional
        float xmm = fs0[rr - 1][cc - 1], xm0 = fs0[rr - 1][cc], xmp = fs0[rr - 1][cc + 1];
        float x0m = fs0[rr][cc - 1], x0p = fs0[rr][cc + 1];
        float xpm = fs0[rr + 1][cc - 1], xp0 = fs0[rr + 1][cc], xpp = fs0[rr + 1][cc + 1];
        float ex = (xmp - xmm) + 2.0f * (x0p - x0m) + (xpp - xpm);
        float ey = (xpm + 2.0f * xp0 + xpp) - (xmm + 2.0f * xm0 + xmp);
        float e45 = -2.0f * xmm - xm0 - x0m + x0p + xp0 + 2.0f * xpp;
        float e135 = xm0 + 2.0f * xmp - x0m + x0p - 2.0f * xpm - xp0;
        ms[y][x] = sqrtf(ex * ex + ey * ey + e45 * e45 + e135 * e135);
        if (y >= 1 && y <= TY && x >= 1 && x <= TX) {
            exs[y - 1][x - 1] = ex;
            eys[y - 1][x - 1] = ey;
        }
    }
    __syncthreads();

    float bmax = 0.0f;
#pragma unroll
    for (int q = 0; q < TY / 4; q++) {
        int yl = threadIdx.y + q * 4;
        int xl = threadIdx.x;
        float ex = exs[yl][xl], ey = eys[yl][xl];

        // fast mod-pi line angle
        float ax = fabsf(ex), ay = fabsf(ey);
        float mn = fminf(ax, ay), mxv = fmaxf(ax, ay);
        float tq = (mxv > 0.0f) ? __fdividef(mn, mxv) : 0.0f;
        float pang = atan_poly(tq);
        if (ay > ax) pang = 1.57079632679f - pang;
        bool obtuse = ((__float_as_uint(ex) ^ __float_as_uint(ey)) & 0x80000000u) != 0u;
        float a = obtuse ? PI_F - pang : pang;

        // nearest + second-nearest direction; other two weigh <= e^(-25*pi)
        float fa = a * 1.27323954474f;          // a * 4/pi  in [0,4]
        float nf = floorf(fa + 0.5f);           // 0..4
        float diff = a - nf * 0.78539816340f;
        float delta = fabsf(diff);
        int n = (int)nf & 3;
        int m = ((diff >= 0.0f) ? (int)nf + 1 : (int)nf - 1) & 3;
        float t = __expf(200.0f * delta - 78.5398163397f);   // e^{-100(pi/4-2delta)} <= 1
        float u = __fdividef(1.0f, 1.0f + t);

        float m0 = ms[yl + 1][xl + 1];
        float n1a = ms[yl + 1][xl], n1b = ms[yl][xl], n1c = ms[yl][xl + 1], n1d = ms[yl][xl + 2];
        float n2a = ms[yl + 1][xl + 2], n2b = ms[yl + 2][xl + 2], n2c = ms[yl + 2][xl + 1], n2d = ms[yl + 2][xl];
        float n1n = sel4(n, n1a, n1b, n1c, n1d);
        float n2n = sel4(n, n2a, n2b, n2c, n2d);
        float n1m = sel4(m, n1a, n1b, n1c, n1d);
        float n2m = sel4(m, n2a, n2b, n2c, n2d);

        float g1n = __expf((n1n - m0) * 10.0f);
        float g2n = __expf((n2n - m0) * 10.0f);
        float g1m = __expf((n1m - m0) * 10.0f);
        float g2m = __expf((n2m - m0) * 10.0f);
        float swn = __fdividef(1.0f, 1.0f + g1n + g2n);
        float swm = __fdividef(1.0f, 1.0f + g1m + g2m);
        float s = m0 * u * (swn + t * swm);

        sup[(size_t)p * HW + (i0 + yl) * W + (j0 + xl)] = s;
        bmax = fmaxf(bmax, s);

        // median histogram: sob quantized, bins over [0,2)
        float sv = 0.5f * (ax + ay);
        int bin = min((int)(sv * BIN_SCALE), NBINS - 1);
        atomicAdd(&histS[bin], 1u);
    }

    float wv = wave_max(bmax);
    if ((tid & 63) == 0) wred[tid >> 6] = wv;
    __syncthreads();
    if (tid == 0) {
        int bflat = (blockIdx.z * gridDim.y + blockIdx.y) * gridDim.x + blockIdx.x;
        pmax[bflat] = fmaxf(fmaxf(wred[0], wred[1]), fmaxf(wred[2], wred[3]));
    }
    for (int e = tid; e < NBINS; e += 256)
        if (histS[e]) atomicAdd(&hist[p * NBINS + e], histS[e]);
}

// blocks 0..15: per-plane median pick; blocks 16..17: per-set sup max reduce
__global__ void K_stats(const unsigned* __restrict__ hist, const float* __restrict__ pmax,
                        float* __restrict__ medv, float* __restrict__ mx) {
    int b = blockIdx.x;
    int t = threadIdx.x;
    if (b < NP) {
        __shared__ unsigned sums[256];
        const unsigned* hp = hist + b * NBINS;
        unsigned s = 0;
        for (int q = 0; q < NBINS / 256; q++) s += hp[t * (NBINS / 256) + q];
        sums[t] = s;
        __syncthreads();
        for (int off = 1; off < 256; off <<= 1) {
            unsigned v = (t >= off) ? sums[t - off] : 0u;
            __syncthreads();
            sums[t] += v;
            __syncthreads();
        }
        const int k = (HW - 1) / 2;
        unsigned base = (t == 0) ? 0u : sums[t - 1];
        if ((int)base <= k && k < (int)sums[t]) {
            int cum = (int)base;
            int bin = t * (NBINS / 256);
            for (int q = 0; q < NBINS / 256; q++) {
                int c = (int)hp[t * (NBINS / 256) + q];
                if (cum + c > k) { bin = t * (NBINS / 256) + q; break; }
                cum += c;
            }
            medv[b] = ((float)bin + 0.5f) * (1.0f / BIN_SCALE);
        }
    } else {
        __shared__ float red[256];
        int s = b - NP;
        const float* base = pmax + s * (NBLK / 2);
        float v = -1e30f;
        for (int i = t; i < NBLK / 2; i += 256) v = fmaxf(v, base[i]);
        red[t] = v;
        __syncthreads();
        for (int sft = 128; sft > 0; sft >>= 1) {
            if (t < sft) red[t] = fmaxf(red[t], red[t + sft]);
            __syncthreads();
        }
        if (t == 0) mx[s] = red[0];
    }
}

// hysteresis combine + dilation + sobel(original) blend; 4 adjacent rows/thread
__global__ void K_result(const float* __restrict__ sup, const float* __restrict__ im1,
                         const float* __restrict__ im2, const float* __restrict__ medv,
                         const float* __restrict__ sg1, const float* __restrict__ ew1,
                         const float* __restrict__ sg2, const float* __restrict__ ew2,
                         const float* __restrict__ mx, float* __restrict__ res,
                         float* __restrict__ prmax, float* __restrict__ prmin) {
    int p = blockIdx.z;
    int s = p >> 3;
    // thresholds computed per block (tiny)
    float med = 0.125f * (medv[s * PPS + 0] + medv[s * PPS + 1] + medv[s * PPS + 2] +
                          medv[s * PPS + 3] + medv[s * PPS + 4] + medv[s * PPS + 5] +
                          medv[s * PPS + 6] + medv[s * PPS + 7]);
    float sgin = (s == 0) ? sg1[0] : sg2[0];
    float ewin = (s == 0) ? ew1[0] : ew2[0];
    float sig = 1.0f - 1.0f / (1.0f + __expf(-sgin));
    float lo = fminf(fmaxf((1.0f - sig) * med, 0.001f), 1.0f);
    float hi = fminf(fmaxf((1.0f + sig) * med, 0.001f), 1.0f);
    float wg = 1.0f / (1.0f + __expf(-ewin));
    float m = mx[s];
    float inv = 1.0f / ((m > 0.0f) ? m : 1.0f);

    const float* sp = sup + (size_t)p * HW;
    const float* op = plane_ptr(im1, im2, p);
    int j0 = blockIdx.x * TX, i0 = blockIdx.y * TY;
    __shared__ float hs2[TY + 2][TX + 2];   // hsw(sup_norm - hi), zero outside image
    __shared__ float ssn[TY][TX];           // normalized sup, interior
    __shared__ float og[TY + 2][TX + 2];    // original image, zero outside
    __shared__ float wredx[4], wredn[4];
    int tid = threadIdx.y * 64 + threadIdx.x;

    for (int e = tid; e < (TY + 2) * (TX + 2); e += 256) {
        int y = e / (TX + 2), x = e % (TX + 2);
        int gi = i0 - 1 + y, gj = j0 - 1 + x;
        float h = 0.0f, o = 0.0f;
        if (gi >= 0 && gi < H && gj >= 0 && gj < W) {
            float sv = sp[gi * W + gj] * inv;
            h = hsw(sv - hi);
            o = op[gi * W + gj];
            if (y >= 1 && y <= TY && x >= 1 && x <= TX) ssn[y - 1][x - 1] = sv;
        }
        hs2[y][x] = h;
        og[y][x] = o;
    }
    __syncthreads();

    int yl = threadIdx.y * 4;
    int xl = threadIdx.x;
    // row sums of h and og pieces for rows yl..yl+5
    float hrow[6], ddr[6], ssr[6];
#pragma unroll
    for (int k = 0; k < 6; k++) {
        float a = hs2[yl + k][xl], bq = hs2[yl + k][xl + 1], c = hs2[yl + k][xl + 2];
        hrow[k] = a + bq + c;
        float oa = og[yl + k][xl], ob = og[yl + k][xl + 1], oc = og[yl + k][xl + 2];
        ddr[k] = oc - oa;
        ssr[k] = oa + 2.0f * ob + oc;
    }

    float bmx = -1e30f, bmn = 1e30f;
    size_t gbase = (size_t)p * HW + (i0 + yl) * W + (j0 + xl);
#pragma unroll
    for (int k = 0; k < 4; k++) {
        float sn = ssn[yl + k][xl];
        float Sh = hs2[yl + k + 1][xl + 1];
        float Sl = hsw(sn - lo);
        float dil = hrow[k] + hrow[k + 1] + hrow[k + 2];
        float pre = sn * (Sh + Sl) + dil * Sl * (1.0f - Sh);
        float sob = 0.5f * fabsf(ddr[k] + 2.0f * ddr[k + 1] + ddr[k + 2]) +
                    0.5f * fabsf(ssr[k + 2] - ssr[k]);
        float r = (1.0f - wg) * pre + wg * sob;
        res[gbase + (size_t)k * W] = r;
        bmx = fmaxf(bmx, r);
        bmn = fminf(bmn, r);
    }

    float vx = wave_max(bmx), vn = wave_min(bmn);
    if ((tid & 63) == 0) { wredx[tid >> 6] = vx; wredn[tid >> 6] = vn; }
    __syncthreads();
    if (tid == 0) {
        int bflat = (blockIdx.z * gridDim.y + blockIdx.y) * gridDim.x + blockIdx.x;
        prmax[bflat] = fmaxf(fmaxf(wredx[0], wredx[1]), fmaxf(wredx[2], wredx[3]));
        prmin[bflat] = fminf(fminf(wredn[0], wredn[1]), fminf(wredn[2], wredn[3]));
    }
}

__global__ void K_redminmax(const float* __restrict__ prmax, const float* __restrict__ prmin,
                            float* __restrict__ rmaxv, float* __restrict__ rminv) {
    __shared__ float rmx[256], rmn[256];
    int t = threadIdx.x;
    for (int s = 0; s < 2; s++) {
        const float* bx = prmax + s * (NBLK / 2);
        const float* bn = prmin + s * (NBLK / 2);
        float vx = -1e30f, vn = 1e30f;
        for (int i = t; i < NBLK / 2; i += 256) {
            vx = fmaxf(vx, bx[i]);
            vn = fminf(vn, bn[i]);
        }
        rmx[t] = vx;
        rmn[t] = vn;
        __syncthreads();
        for (int sft = 128; sft > 0; sft >>= 1) {
            if (t < sft) {
                rmx[t] = fmaxf(rmx[t], rmx[t + sft]);
                rmn[t] = fminf(rmn[t], rmn[t + sft]);
            }
            __syncthreads();
        }
        if (t == 0) { rmaxv[s] = rmx[0]; rminv[s] = rmn[0]; }
        __syncthreads();
    }
}

__global__ void K_final(const float* __restrict__ res, const float* __restrict__ rmaxv,
                        const float* __restrict__ rminv, float* __restrict__ out) {
    int j = blockIdx.x * 64 + threadIdx.x;
    int i = blockIdx.y * 4 + threadIdx.y;
    int p = blockIdx.z;  // 0..7
    float mx1 = rmaxv[0], mn1 = rminv[0];
    float mx2 = rmaxv[1], mn2 = rminv[1];
    size_t idx = (size_t)p * HW + i * W + j;
    float r1 = res[idx];
    float r2 = res[(size_t)(p + PPS) * HW + i * W + j];
    float m1 = (r1 - mn1) / (mx1 - mn1);
    float m2 = (r2 - mn2) / (mx2 - mn2);
    out[idx] = m1 + m2 - 2.0f * m1 * m2;               // 1 - f
    out[(size_t)PPS * HW + idx] = m1;
    out[(size_t)2 * PPS * HW + idx] = m2;
}

}  // namespace

extern "C" void kernel_launch(void* const* d_in, const int* in_sizes, int n_in,
                              void* d_out, int out_size, void* d_ws, size_t ws_size,
                              hipStream_t stream) {
    const float* img1 = (const float*)d_in[0];
    const float* img2 = (const float*)d_in[1];
    const float* sg1 = (const float*)d_in[2];
    const float* ew1 = (const float*)d_in[3];
    const float* sg2 = (const float*)d_in[4];
    const float* ew2 = (const float*)d_in[5];
    float* out = (float*)d_out;

    float* A = (float*)d_ws;                             // ping / blurred
    float* B = A + (size_t)NP * HW;                      // pong / res
    float* C = B + (size_t)NP * HW;                      // sup
    unsigned* hist = (unsigned*)(C + (size_t)NP * HW);   // NP*NBINS
    float* medv = (float*)(hist + NP * NBINS);           // 16
    float* mx = medv + NP;
    float* rmaxv = mx + 2;
    float* rminv = rmaxv + 2;
    float* pmax = rminv + 2;           // NBLK
    float* prmax = pmax + NBLK;        // NBLK
    float* prmin = prmax + NBLK;       // NBLK

    dim3 blk(64, 4, 1);
    dim3 grdT(W / TX, H / TY, NP);     // dnms / result (4096 blocks)
    dim3 grdS(W / 64, H / STY, NP);    // smooth
    dim3 grdF(W / 64, H / 4, PPS);     // final
    dim3 mblk(256, 1, 1);

    K_init<<<dim3(16), mblk, 0, stream>>>(hist);

    // adaptive smoothing: 3 iterations  in->A, A->B, B->A  (blurred -> A)
    K_smooth<<<grdS, blk, 0, stream>>>(img1, img2, A);
    K_smooth<<<grdS, blk, 0, stream>>>(A, A + (size_t)PPS * HW, B);
    K_smooth<<<grdS, blk, 0, stream>>>(B, B + (size_t)PPS * HW, A);

    // fused derivs+NMS+median-hist: A -> sup(C), hist, pmax
    K_dnms<<<grdT, blk, 0, stream>>>(A, C, hist, pmax);

    // per-plane medians + per-set sup max in one dispatch
    K_stats<<<dim3(NP + 2), mblk, 0, stream>>>(hist, pmax, medv, mx);

    K_result<<<grdT, blk, 0, stream>>>(C, img1, img2, medv, sg1, ew1, sg2, ew2, mx,
                                       B, prmax, prmin);
    K_redminmax<<<dim3(1), mblk, 0, stream>>>(prmax, prmin, rmaxv, rminv);
    K_final<<<grdF, blk, 0, stream>>>(B, rmaxv, rminv, out);
}

// Round 9
// 120.035 us; speedup vs baseline: 1.7432x; 1.0861x over previous
//
#include <hip/hip_runtime.h>

namespace {

constexpr int H = 512;
constexpr int W = 512;
constexpr int HW = H * W;
constexpr int PPS = 8;    // planes per canny set
constexpr int NP = 16;    // total planes (2 sets x 8)
constexpr int TX = 64;    // tile width (dnms/result)
constexpr int TY = 16;    // tile height (dnms/result): 4 adjacent rows/thread
constexpr int STY = 16;   // smooth tile height
constexpr int NBLK = (W / TX) * (H / TY) * NP;   // 4096
constexpr float PI_F = 3.14159265358979323846f;
constexpr int NBINS = 1024;                 // median bins over [0,2)
constexpr float BIN_SCALE = 512.0f;

__device__ __forceinline__ float hsw(float x) {
    float t = fminf(fmaxf(x + 3.0f, 0.0f), 6.0f);
    return x * t * (1.0f / 6.0f);
}

__device__ __forceinline__ const float* plane_ptr(const float* s1, const float* s2, int p) {
    return (p < PPS) ? (s1 + (size_t)p * HW) : (s2 + (size_t)(p - PPS) * HW);
}

__device__ __forceinline__ float wave_max(float v) {
    for (int o = 32; o > 0; o >>= 1) v = fmaxf(v, __shfl_down(v, o, 64));
    return v;
}
__device__ __forceinline__ float wave_min(float v) {
    for (int o = 32; o > 0; o >>= 1) v = fminf(v, __shfl_down(v, o, 64));
    return v;
}

// minimax atan on [0,1], err ~2e-7
__device__ __forceinline__ float atan_poly(float t) {
    float z = t * t;
    float p = -0.01172120f;
    p = p * z + 0.05265332f;
    p = p * z - 0.11643287f;
    p = p * z + 0.19354346f;
    p = p * z - 0.33262347f;
    p = p * z + 0.99997726f;
    return t * p;
}

// 4-to-1 mux with static code (no runtime-indexed arrays)
__device__ __forceinline__ float sel4(int idx, float v0, float v1, float v2, float v3) {
    float a = (idx & 1) ? v1 : v0;
    float b = (idx & 1) ? v3 : v2;
    return (idx & 2) ? b : a;
}

// One adaptive-smoothing iteration; 16-row tile, 4 adjacent rows per thread.
// First dispatch also zeroes the median histogram (hist != nullptr).
__global__ void K_smooth(const float* __restrict__ s1, const float* __restrict__ s2,
                         float* __restrict__ fout, unsigned* __restrict__ hist) {
    int tid = threadIdx.y * 64 + threadIdx.x;
    if (hist) {
        int bid = (blockIdx.z * gridDim.y + blockIdx.y) * gridDim.x + blockIdx.x;
        if (bid < (NP * NBINS) / 256) hist[bid * 256 + tid] = 0;
    }
    int p = blockIdx.z;
    const float* f = plane_ptr(s1, s2, p);
    int j0 = blockIdx.x * 64, i0 = blockIdx.y * STY;
    __shared__ float fs[STY + 4][68];   // f[clip(i0-2+y)][clip(j0-2+x)]
    __shared__ float ws[STY + 2][66];   // w(clip(i0-1+y), clip(j0-1+x))

    for (int e = tid; e < (STY + 4) * 68; e += 256) {
        int y = e / 68, x = e % 68;
        int gi = min(max(i0 - 2 + y, 0), H - 1);
        int gj = min(max(j0 - 2 + x, 0), W - 1);
        fs[y][x] = f[gi * W + gj];
    }
    __syncthreads();

    for (int e = tid; e < (STY + 2) * 66; e += 256) {
        int y = e / 66, x = e % 66;
        int r = min(max(i0 - 1 + y, 0), H - 1);   // w evaluated at CLIPPED coords
        int c = min(max(j0 - 1 + x, 0), W - 1);
        int yr = r - (i0 - 2), xc = c - (j0 - 2);
        int ym = max(r - 1, 0) - (i0 - 2), yp = min(r + 1, H - 1) - (i0 - 2);
        int xm = max(c - 1, 0) - (j0 - 2), xp = min(c + 1, W - 1) - (j0 - 2);
        float gx = 0.5f * (fs[yp][xc] - fs[ym][xc]);
        float gy = 0.5f * (fs[yr][xp] - fs[yr][xm]);
        ws[y][x] = __expf(-(gx * gx + gy * gy) * (1.0f / 200.0f));
    }
    __syncthreads();

    int yl = threadIdx.y * 4;
    int xl = threadIdx.x;
    float rn[6], rd[6];
#pragma unroll
    for (int k = 0; k < 6; k++) {
        float w0 = ws[yl + k][xl], w1 = ws[yl + k][xl + 1], w2 = ws[yl + k][xl + 2];
        float fA = fs[yl + k + 1][xl + 1], fB = fs[yl + k + 1][xl + 2], fC = fs[yl + k + 1][xl + 3];
        rn[k] = fA * w0 + fB * w1 + fC * w2;
        rd[k] = w0 + w1 + w2;
    }
    size_t base = (size_t)p * HW + (i0 + yl) * W + (j0 + xl);
#pragma unroll
    for (int k = 0; k < 4; k++) {
        fout[base + (size_t)k * W] =
            (rn[k] + rn[k + 1] + rn[k + 2]) / fmaxf(rd[k] + rd[k + 1] + rd[k + 2], 1e-8f);
    }
}

// fused derivatives + NMS (2-direction softmax) + median histogram.
// Interior derivatives live in registers; only mag goes through LDS.
__global__ void K_dnms(const float* __restrict__ blur, float* __restrict__ sup,
                       unsigned* __restrict__ hist, float* __restrict__ pmax) {
    int p = blockIdx.z;
    const float* f = blur + (size_t)p * HW;
    int j0 = blockIdx.x * TX, i0 = blockIdx.y * TY;
    __shared__ float fs0[TY + 4][TX + 4];   // ZERO-padded blur at absolute coords
    __shared__ float ms[TY + 2][TX + 2];    // mag at clipped coords
    __shared__ unsigned histS[NBINS];
    __shared__ float wred[4];
    int tid = threadIdx.y * 64 + threadIdx.x;

    for (int e = tid; e < NBINS; e += 256) histS[e] = 0;
    for (int e = tid; e < (TY + 4) * (TX + 4); e += 256) {
        int y = e / (TX + 4), x = e % (TX + 4);
        int gi = i0 - 2 + y, gj = j0 - 2 + x;
        fs0[y][x] = (gi >= 0 && gi < H && gj >= 0 && gj < W) ? f[gi * W + gj] : 0.0f;
    }
    __syncthreads();

    int xl = threadIdx.x;
    int yb = threadIdx.y * 4;

    // interior: this thread's 4 adjacent pixels; derivatives in registers
    float fv[6][3];
#pragma unroll
    for (int rr = 0; rr < 6; rr++)
#pragma unroll
        for (int cc = 0; cc < 3; cc++)
            fv[rr][cc] = fs0[yb + 1 + rr][xl + 1 + cc];

    float exk[4], eyk[4];
#pragma unroll
    for (int k = 0; k < 4; k++) {
        float xmm = fv[k][0], xm0 = fv[k][1], xmp = fv[k][2];
        float x0m = fv[k + 1][0], x0p = fv[k + 1][2];
        float xpm = fv[k + 2][0], xp0 = fv[k + 2][1], xpp = fv[k + 2][2];
        float ex = (xmp - xmm) + 2.0f * (x0p - x0m) + (xpp - xpm);
        float ey = (xpm + 2.0f * xp0 + xpp) - (xmm + 2.0f * xm0 + xmp);
        float e45 = -2.0f * xmm - xm0 - x0m + x0p + xp0 + 2.0f * xpp;
        float e135 = xm0 + 2.0f * xmp - x0m + x0p - 2.0f * xpm - xp0;
        ms[yb + 1 + k][xl + 1] = sqrtf(ex * ex + ey * ey + e45 * e45 + e135 * e135);
        exk[k] = ex;
        eyk[k] = ey;
    }

    // halo mag entries (164 of them), clip semantics
    if (tid < 2 * (TX + 2) + 2 * TY) {
        int y, x;
        if (tid < TX + 2) { y = 0; x = tid; }
        else if (tid < 2 * (TX + 2)) { y = TY + 1; x = tid - (TX + 2); }
        else if (tid < 2 * (TX + 2) + TY) { y = tid - 2 * (TX + 2) + 1; x = 0; }
        else { y = tid - (2 * (TX + 2) + TY) + 1; x = TX + 1; }
        int r = min(max(i0 - 1 + y, 0), H - 1);
        int c = min(max(j0 - 1 + x, 0), W - 1);
        int rr = r - i0 + 2, cc = c - j0 + 2;
        float xmm = fs0[rr - 1][cc - 1], xm0 = fs0[rr - 1][cc], xmp = fs0[rr - 1][cc + 1];
        float x0m = fs0[rr][cc - 1], x0p = fs0[rr][cc + 1];
        float xpm = fs0[rr + 1][cc - 1], xp0 = fs0[rr + 1][cc], xpp = fs0[rr + 1][cc + 1];
        float ex = (xmp - xmm) + 2.0f * (x0p - x0m) + (xpp - xpm);
        float ey = (xpm + 2.0f * xp0 + xpp) - (xmm + 2.0f * xm0 + xmp);
        float e45 = -2.0f * xmm - xm0 - x0m + x0p + xp0 + 2.0f * xpp;
        float e135 = xm0 + 2.0f * xmp - x0m + x0p - 2.0f * xpm - xp0;
        ms[y][x] = sqrtf(ex * ex + ey * ey + e45 * e45 + e135 * e135);
    }
    __syncthreads();

    // 6x3 mag register block covering the 4 pixels' 3x3 neighborhoods
    float msr[6][3];
#pragma unroll
    for (int rr = 0; rr < 6; rr++)
#pragma unroll
        for (int cc = 0; cc < 3; cc++)
            msr[rr][cc] = ms[yb + rr][xl + cc];

    float bmax = 0.0f;
#pragma unroll
    for (int k = 0; k < 4; k++) {
        float ex = exk[k], ey = eyk[k];

        // fast mod-pi line angle
        float ax = fabsf(ex), ay = fabsf(ey);
        float mn = fminf(ax, ay), mxv = fmaxf(ax, ay);
        float tq = (mxv > 0.0f) ? __fdividef(mn, mxv) : 0.0f;
        float pang = atan_poly(tq);
        if (ay > ax) pang = 1.57079632679f - pang;
        bool obtuse = ((__float_as_uint(ex) ^ __float_as_uint(ey)) & 0x80000000u) != 0u;
        float a = obtuse ? PI_F - pang : pang;

        // nearest + second-nearest direction; other two weigh <= e^(-25*pi)
        float fa = a * 1.27323954474f;          // a * 4/pi  in [0,4]
        float nf = floorf(fa + 0.5f);           // 0..4
        float diff = a - nf * 0.78539816340f;
        float delta = fabsf(diff);
        int n = (int)nf & 3;
        int m = ((diff >= 0.0f) ? (int)nf + 1 : (int)nf - 1) & 3;
        float t = __expf(200.0f * delta - 78.5398163397f);   // e^{-100(pi/4-2delta)} <= 1
        float u = __fdividef(1.0f, 1.0f + t);

        float m0 = msr[k + 1][1];
        float n1a = msr[k + 1][0], n1b = msr[k][0], n1c = msr[k][1], n1d = msr[k][2];
        float n2a = msr[k + 1][2], n2b = msr[k + 2][2], n2c = msr[k + 2][1], n2d = msr[k + 2][0];
        float n1n = sel4(n, n1a, n1b, n1c, n1d);
        float n2n = sel4(n, n2a, n2b, n2c, n2d);
        float n1m = sel4(m, n1a, n1b, n1c, n1d);
        float n2m = sel4(m, n2a, n2b, n2c, n2d);

        float g1n = __expf((n1n - m0) * 10.0f);
        float g2n = __expf((n2n - m0) * 10.0f);
        float g1m = __expf((n1m - m0) * 10.0f);
        float g2m = __expf((n2m - m0) * 10.0f);
        float swn = __fdividef(1.0f, 1.0f + g1n + g2n);
        float swm = __fdividef(1.0f, 1.0f + g1m + g2m);
        float s = m0 * u * (swn + t * swm);

        sup[(size_t)p * HW + (i0 + yb + k) * W + (j0 + xl)] = s;
        bmax = fmaxf(bmax, s);

        // median histogram: sob quantized, bins over [0,2)
        float sv = 0.5f * (ax + ay);
        int bin = min((int)(sv * BIN_SCALE), NBINS - 1);
        atomicAdd(&histS[bin], 1u);
    }

    float wv = wave_max(bmax);
    if ((tid & 63) == 0) wred[tid >> 6] = wv;
    __syncthreads();
    if (tid == 0) {
        int bflat = (blockIdx.z * gridDim.y + blockIdx.y) * gridDim.x + blockIdx.x;
        pmax[bflat] = fmaxf(fmaxf(wred[0], wred[1]), fmaxf(wred[2], wred[3]));
    }
    for (int e = tid; e < NBINS; e += 256)
        if (histS[e]) atomicAdd(&hist[p * NBINS + e], histS[e]);
}

// blocks 0..15: per-plane median pick; blocks 16..17: per-set sup max reduce
__global__ void K_stats(const unsigned* __restrict__ hist, const float* __restrict__ pmax,
                        float* __restrict__ medv, float* __restrict__ mx) {
    int b = blockIdx.x;
    int t = threadIdx.x;
    if (b < NP) {
        __shared__ unsigned sums[256];
        const unsigned* hp = hist + b * NBINS;
        unsigned s = 0;
        for (int q = 0; q < NBINS / 256; q++) s += hp[t * (NBINS / 256) + q];
        sums[t] = s;
        __syncthreads();
        for (int off = 1; off < 256; off <<= 1) {
            unsigned v = (t >= off) ? sums[t - off] : 0u;
            __syncthreads();
            sums[t] += v;
            __syncthreads();
        }
        const int k = (HW - 1) / 2;
        unsigned base = (t == 0) ? 0u : sums[t - 1];
        if ((int)base <= k && k < (int)sums[t]) {
            int cum = (int)base;
            int bin = t * (NBINS / 256);
            for (int q = 0; q < NBINS / 256; q++) {
                int c = (int)hp[t * (NBINS / 256) + q];
                if (cum + c > k) { bin = t * (NBINS / 256) + q; break; }
                cum += c;
            }
            medv[b] = ((float)bin + 0.5f) * (1.0f / BIN_SCALE);
        }
    } else {
        __shared__ float red[256];
        int s = b - NP;
        const float* base = pmax + s * (NBLK / 2);
        float v = -1e30f;
        for (int i = t; i < NBLK / 2; i += 256) v = fmaxf(v, base[i]);
        red[t] = v;
        __syncthreads();
        for (int sft = 128; sft > 0; sft >>= 1) {
            if (t < sft) red[t] = fmaxf(red[t], red[t + sft]);
            __syncthreads();
        }
        if (t == 0) mx[s] = red[0];
    }
}

// hysteresis combine + dilation + sobel(original) blend; 4 adjacent rows/thread
__global__ void K_result(const float* __restrict__ sup, const float* __restrict__ im1,
                         const float* __restrict__ im2, const float* __restrict__ medv,
                         const float* __restrict__ sg1, const float* __restrict__ ew1,
                         const float* __restrict__ sg2, const float* __restrict__ ew2,
                         const float* __restrict__ mx, float* __restrict__ res,
                         float* __restrict__ prmax, float* __restrict__ prmin) {
    int p = blockIdx.z;
    int s = p >> 3;
    float med = 0.125f * (medv[s * PPS + 0] + medv[s * PPS + 1] + medv[s * PPS + 2] +
                          medv[s * PPS + 3] + medv[s * PPS + 4] + medv[s * PPS + 5] +
                          medv[s * PPS + 6] + medv[s * PPS + 7]);
    float sgin = (s == 0) ? sg1[0] : sg2[0];
    float ewin = (s == 0) ? ew1[0] : ew2[0];
    float sig = 1.0f - 1.0f / (1.0f + __expf(-sgin));
    float lo = fminf(fmaxf((1.0f - sig) * med, 0.001f), 1.0f);
    float hi = fminf(fmaxf((1.0f + sig) * med, 0.001f), 1.0f);
    float wg = 1.0f / (1.0f + __expf(-ewin));
    float m = mx[s];
    float inv = 1.0f / ((m > 0.0f) ? m : 1.0f);

    const float* sp = sup + (size_t)p * HW;
    const float* op = plane_ptr(im1, im2, p);
    int j0 = blockIdx.x * TX, i0 = blockIdx.y * TY;
    __shared__ float hs2[TY + 2][TX + 2];   // hsw(sup_norm - hi), zero outside image
    __shared__ float ssn[TY][TX];           // normalized sup, interior
    __shared__ float og[TY + 2][TX + 2];    // original image, zero outside
    __shared__ float wredx[4], wredn[4];
    int tid = threadIdx.y * 64 + threadIdx.x;

    for (int e = tid; e < (TY + 2) * (TX + 2); e += 256) {
        int y = e / (TX + 2), x = e % (TX + 2);
        int gi = i0 - 1 + y, gj = j0 - 1 + x;
        float h = 0.0f, o = 0.0f;
        if (gi >= 0 && gi < H && gj >= 0 && gj < W) {
            float sv = sp[gi * W + gj] * inv;
            h = hsw(sv - hi);
            o = op[gi * W + gj];
            if (y >= 1 && y <= TY && x >= 1 && x <= TX) ssn[y - 1][x - 1] = sv;
        }
        hs2[y][x] = h;
        og[y][x] = o;
    }
    __syncthreads();

    int yl = threadIdx.y * 4;
    int xl = threadIdx.x;
    float hrow[6], ddr[6], ssr[6];
#pragma unroll
    for (int k = 0; k < 6; k++) {
        float a = hs2[yl + k][xl], bq = hs2[yl + k][xl + 1], c = hs2[yl + k][xl + 2];
        hrow[k] = a + bq + c;
        float oa = og[yl + k][xl], ob = og[yl + k][xl + 1], oc = og[yl + k][xl + 2];
        ddr[k] = oc - oa;
        ssr[k] = oa + 2.0f * ob + oc;
    }

    float bmx = -1e30f, bmn = 1e30f;
    size_t gbase = (size_t)p * HW + (i0 + yl) * W + (j0 + xl);
#pragma unroll
    for (int k = 0; k < 4; k++) {
        float sn = ssn[yl + k][xl];
        float Sh = hs2[yl + k + 1][xl + 1];
        float Sl = hsw(sn - lo);
        float dil = hrow[k] + hrow[k + 1] + hrow[k + 2];
        float pre = sn * (Sh + Sl) + dil * Sl * (1.0f - Sh);
        float sob = 0.5f * fabsf(ddr[k] + 2.0f * ddr[k + 1] + ddr[k + 2]) +
                    0.5f * fabsf(ssr[k + 2] - ssr[k]);
        float r = (1.0f - wg) * pre + wg * sob;
        res[gbase + (size_t)k * W] = r;
        bmx = fmaxf(bmx, r);
        bmn = fminf(bmn, r);
    }

    float vx = wave_max(bmx), vn = wave_min(bmn);
    if ((tid & 63) == 0) { wredx[tid >> 6] = vx; wredn[tid >> 6] = vn; }
    __syncthreads();
    if (tid == 0) {
        int bflat = (blockIdx.z * gridDim.y + blockIdx.y) * gridDim.x + blockIdx.x;
        prmax[bflat] = fmaxf(fmaxf(wredx[0], wredx[1]), fmaxf(wredx[2], wredx[3]));
        prmin[bflat] = fminf(fminf(wredn[0], wredn[1]), fminf(wredn[2], wredn[3]));
    }
}

__global__ void K_redminmax(const float* __restrict__ prmax, const float* __restrict__ prmin,
                            float* __restrict__ rmaxv, float* __restrict__ rminv) {
    __shared__ float rmx[256], rmn[256];
    int t = threadIdx.x;
    for (int s = 0; s < 2; s++) {
        const float* bx = prmax + s * (NBLK / 2);
        const float* bn = prmin + s * (NBLK / 2);
        float vx = -1e30f, vn = 1e30f;
        for (int i = t; i < NBLK / 2; i += 256) {
            vx = fmaxf(vx, bx[i]);
            vn = fminf(vn, bn[i]);
        }
        rmx[t] = vx;
        rmn[t] = vn;
        __syncthreads();
        for (int sft = 128; sft > 0; sft >>= 1) {
            if (t < sft) {
                rmx[t] = fmaxf(rmx[t], rmx[t + sft]);
                rmn[t] = fminf(rmn[t], rmn[t + sft]);
            }
            __syncthreads();
        }
        if (t == 0) { rmaxv[s] = rmx[0]; rminv[s] = rmn[0]; }
        __syncthreads();
    }
}

__global__ void K_final(const float* __restrict__ res, const float* __restrict__ rmaxv,
                        const float* __restrict__ rminv, float* __restrict__ out) {
    int j = blockIdx.x * 64 + threadIdx.x;
    int i = blockIdx.y * 4 + threadIdx.y;
    int p = blockIdx.z;  // 0..7
    float mx1 = rmaxv[0], mn1 = rminv[0];
    float mx2 = rmaxv[1], mn2 = rminv[1];
    size_t idx = (size_t)p * HW + i * W + j;
    float r1 = res[idx];
    float r2 = res[(size_t)(p + PPS) * HW + i * W + j];
    float m1 = (r1 - mn1) / (mx1 - mn1);
    float m2 = (r2 - mn2) / (mx2 - mn2);
    out[idx] = m1 + m2 - 2.0f * m1 * m2;               // 1 - f
    out[(size_t)PPS * HW + idx] = m1;
    out[(size_t)2 * PPS * HW + idx] = m2;
}

}  // namespace

extern "C" void kernel_launch(void* const* d_in, const int* in_sizes, int n_in,
                              void* d_out, int out_size, void* d_ws, size_t ws_size,
                              hipStream_t stream) {
    const float* img1 = (const float*)d_in[0];
    const float* img2 = (const float*)d_in[1];
    const float* sg1 = (const float*)d_in[2];
    const float* ew1 = (const float*)d_in[3];
    const float* sg2 = (const float*)d_in[4];
    const float* ew2 = (const float*)d_in[5];
    float* out = (float*)d_out;

    float* A = (float*)d_ws;                             // ping / blurred
    float* B = A + (size_t)NP * HW;                      // pong / res
    float* C = B + (size_t)NP * HW;                      // sup
    unsigned* hist = (unsigned*)(C + (size_t)NP * HW);   // NP*NBINS
    float* medv = (float*)(hist + NP * NBINS);           // 16
    float* mx = medv + NP;
    float* rmaxv = mx + 2;
    float* rminv = rmaxv + 2;
    float* pmax = rminv + 2;           // NBLK
    float* prmax = pmax + NBLK;        // NBLK
    float* prmin = prmax + NBLK;       // NBLK

    dim3 blk(64, 4, 1);
    dim3 grdT(W / TX, H / TY, NP);     // dnms / result (4096 blocks)
    dim3 grdS(W / 64, H / STY, NP);    // smooth
    dim3 grdF(W / 64, H / 4, PPS);     // final
    dim3 mblk(256, 1, 1);

    // adaptive smoothing: 3 iterations  in->A, A->B, B->A  (blurred -> A)
    // first dispatch also zeroes the median histogram
    K_smooth<<<grdS, blk, 0, stream>>>(img1, img2, A, hist);
    K_smooth<<<grdS, blk, 0, stream>>>(A, A + (size_t)PPS * HW, B, nullptr);
    K_smooth<<<grdS, blk, 0, stream>>>(B, B + (size_t)PPS * HW, A, nullptr);

    // fused derivs+NMS+median-hist: A -> sup(C), hist, pmax
    K_dnms<<<grdT, blk, 0, stream>>>(A, C, hist, pmax);

    // per-plane medians + per-set sup max in one dispatch
    K_stats<<<dim3(NP + 2), mblk, 0, stream>>>(hist, pmax, medv, mx);

    K_result<<<grdT, blk, 0, stream>>>(C, img1, img2, medv, sg1, ew1, sg2, ew2, mx,
                                       B, prmax, prmin);
    K_redminmax<<<dim3(1), mblk, 0, stream>>>(prmax, prmin, rmaxv, rminv);
    K_final<<<grdF, blk, 0, stream>>>(B, rmaxv, rminv, out);
}

// Round 10
// 112.259 us; speedup vs baseline: 1.8639x; 1.0693x over previous
//
#include <hip/hip_runtime.h>

namespace {

constexpr int H = 512;
constexpr int W = 512;
constexpr int HW = H * W;
constexpr int PPS = 8;    // planes per canny set
constexpr int NP = 16;    // total planes (2 sets x 8)
constexpr int TX = 64;    // tile width (dnms/result)
constexpr int TY = 16;    // tile height (dnms/result): 4 adjacent rows/thread
constexpr int STY = 16;   // smooth tile height
constexpr int NBLK = (W / TX) * (H / TY) * NP;   // 4096
constexpr int HBLK = NBLK / 2;                   // 2048 per set
constexpr float PI_F = 3.14159265358979323846f;
constexpr int NBINS = 1024;                 // median bins over [0,2)
constexpr float BIN_SCALE = 512.0f;

__device__ __forceinline__ float hsw(float x) {
    float t = fminf(fmaxf(x + 3.0f, 0.0f), 6.0f);
    return x * t * (1.0f / 6.0f);
}

__device__ __forceinline__ const float* plane_ptr(const float* s1, const float* s2, int p) {
    return (p < PPS) ? (s1 + (size_t)p * HW) : (s2 + (size_t)(p - PPS) * HW);
}

__device__ __forceinline__ float wave_max(float v) {
    for (int o = 32; o > 0; o >>= 1) v = fmaxf(v, __shfl_down(v, o, 64));
    return v;
}
__device__ __forceinline__ float wave_min(float v) {
    for (int o = 32; o > 0; o >>= 1) v = fminf(v, __shfl_down(v, o, 64));
    return v;
}

// minimax atan on [0,1], err ~2e-7
__device__ __forceinline__ float atan_poly(float t) {
    float z = t * t;
    float p = -0.01172120f;
    p = p * z + 0.05265332f;
    p = p * z - 0.11643287f;
    p = p * z + 0.19354346f;
    p = p * z - 0.33262347f;
    p = p * z + 0.99997726f;
    return t * p;
}

// 4-to-1 mux with static code (no runtime-indexed arrays)
__device__ __forceinline__ float sel4(int idx, float v0, float v1, float v2, float v3) {
    float a = (idx & 1) ? v1 : v0;
    float b = (idx & 1) ? v3 : v2;
    return (idx & 2) ? b : a;
}

// One adaptive-smoothing iteration; 16-row tile, 4 adjacent rows per thread.
// First dispatch also zeroes the median histogram (hist != nullptr).
__global__ void K_smooth(const float* __restrict__ s1, const float* __restrict__ s2,
                         float* __restrict__ fout, unsigned* __restrict__ hist) {
    int tid = threadIdx.y * 64 + threadIdx.x;
    if (hist) {
        int bid = (blockIdx.z * gridDim.y + blockIdx.y) * gridDim.x + blockIdx.x;
        if (bid < (NP * NBINS) / 256) hist[bid * 256 + tid] = 0;
    }
    int p = blockIdx.z;
    const float* f = plane_ptr(s1, s2, p);
    int j0 = blockIdx.x * 64, i0 = blockIdx.y * STY;
    __shared__ float fs[STY + 4][68];   // f[clip(i0-2+y)][clip(j0-2+x)]
    __shared__ float ws[STY + 2][66];   // w(clip(i0-1+y), clip(j0-1+x))

    // interior: tile + halo2 fully inside the image -> all clip math is identity
    bool interior = (i0 >= 2) && (i0 + STY + 1 <= H - 1) && (j0 >= 2) && (j0 + 65 <= W - 1);

    if (interior) {
        const float* fb = f + (i0 - 2) * W + (j0 - 2);
        for (int e = tid; e < (STY + 4) * 68; e += 256) {
            int y = e / 68, x = e % 68;
            fs[y][x] = fb[y * W + x];
        }
        __syncthreads();
        for (int e = tid; e < (STY + 2) * 66; e += 256) {
            int y = e / 66, x = e % 66;
            float gx = 0.5f * (fs[y + 2][x + 1] - fs[y][x + 1]);
            float gy = 0.5f * (fs[y + 1][x + 2] - fs[y + 1][x]);
            ws[y][x] = __expf(-(gx * gx + gy * gy) * (1.0f / 200.0f));
        }
    } else {
        for (int e = tid; e < (STY + 4) * 68; e += 256) {
            int y = e / 68, x = e % 68;
            int gi = min(max(i0 - 2 + y, 0), H - 1);
            int gj = min(max(j0 - 2 + x, 0), W - 1);
            fs[y][x] = f[gi * W + gj];
        }
        __syncthreads();
        for (int e = tid; e < (STY + 2) * 66; e += 256) {
            int y = e / 66, x = e % 66;
            int r = min(max(i0 - 1 + y, 0), H - 1);   // w evaluated at CLIPPED coords
            int c = min(max(j0 - 1 + x, 0), W - 1);
            int yr = r - (i0 - 2), xc = c - (j0 - 2);
            int ym = max(r - 1, 0) - (i0 - 2), yp = min(r + 1, H - 1) - (i0 - 2);
            int xm = max(c - 1, 0) - (j0 - 2), xp = min(c + 1, W - 1) - (j0 - 2);
            float gx = 0.5f * (fs[yp][xc] - fs[ym][xc]);
            float gy = 0.5f * (fs[yr][xp] - fs[yr][xm]);
            ws[y][x] = __expf(-(gx * gx + gy * gy) * (1.0f / 200.0f));
        }
    }
    __syncthreads();

    int yl = threadIdx.y * 4;
    int xl = threadIdx.x;
    float rn[6], rd[6];
#pragma unroll
    for (int k = 0; k < 6; k++) {
        float w0 = ws[yl + k][xl], w1 = ws[yl + k][xl + 1], w2 = ws[yl + k][xl + 2];
        float fA = fs[yl + k + 1][xl + 1], fB = fs[yl + k + 1][xl + 2], fC = fs[yl + k + 1][xl + 3];
        rn[k] = fA * w0 + fB * w1 + fC * w2;
        rd[k] = w0 + w1 + w2;
    }
    size_t base = (size_t)p * HW + (i0 + yl) * W + (j0 + xl);
#pragma unroll
    for (int k = 0; k < 4; k++) {
        fout[base + (size_t)k * W] =
            (rn[k] + rn[k + 1] + rn[k + 2]) / fmaxf(rd[k] + rd[k + 1] + rd[k + 2], 1e-8f);
    }
}

// fused derivatives + NMS (2-direction softmax) + median histogram.
// Interior derivatives live in registers; only mag goes through LDS.
__global__ void K_dnms(const float* __restrict__ blur, float* __restrict__ sup,
                       unsigned* __restrict__ hist, float* __restrict__ pmax) {
    int p = blockIdx.z;
    const float* f = blur + (size_t)p * HW;
    int j0 = blockIdx.x * TX, i0 = blockIdx.y * TY;
    __shared__ float fs0[TY + 4][TX + 4];   // ZERO-padded blur at absolute coords
    __shared__ float ms[TY + 2][TX + 2];    // mag at clipped coords
    __shared__ unsigned histS[NBINS];
    __shared__ float wred[4];
    int tid = threadIdx.y * 64 + threadIdx.x;

    bool interior = (i0 >= 2) && (i0 + TY + 1 <= H - 1) && (j0 >= 2) && (j0 + TX + 1 <= W - 1);

    for (int e = tid; e < NBINS; e += 256) histS[e] = 0;
    if (interior) {
        const float* fb = f + (i0 - 2) * W + (j0 - 2);
        for (int e = tid; e < (TY + 4) * (TX + 4); e += 256) {
            int y = e / (TX + 4), x = e % (TX + 4);
            fs0[y][x] = fb[y * W + x];
        }
    } else {
        for (int e = tid; e < (TY + 4) * (TX + 4); e += 256) {
            int y = e / (TX + 4), x = e % (TX + 4);
            int gi = i0 - 2 + y, gj = j0 - 2 + x;
            fs0[y][x] = (gi >= 0 && gi < H && gj >= 0 && gj < W) ? f[gi * W + gj] : 0.0f;
        }
    }
    __syncthreads();

    int xl = threadIdx.x;
    int yb = threadIdx.y * 4;

    // interior pixels: this thread's 4 adjacent rows; derivatives in registers
    float fv[6][3];
#pragma unroll
    for (int rr = 0; rr < 6; rr++)
#pragma unroll
        for (int cc = 0; cc < 3; cc++)
            fv[rr][cc] = fs0[yb + 1 + rr][xl + 1 + cc];

    float exk[4], eyk[4];
#pragma unroll
    for (int k = 0; k < 4; k++) {
        float xmm = fv[k][0], xm0 = fv[k][1], xmp = fv[k][2];
        float x0m = fv[k + 1][0], x0p = fv[k + 1][2];
        float xpm = fv[k + 2][0], xp0 = fv[k + 2][1], xpp = fv[k + 2][2];
        float ex = (xmp - xmm) + 2.0f * (x0p - x0m) + (xpp - xpm);
        float ey = (xpm + 2.0f * xp0 + xpp) - (xmm + 2.0f * xm0 + xmp);
        float e45 = -2.0f * xmm - xm0 - x0m + x0p + xp0 + 2.0f * xpp;
        float e135 = xm0 + 2.0f * xmp - x0m + x0p - 2.0f * xpm - xp0;
        ms[yb + 1 + k][xl + 1] = sqrtf(ex * ex + ey * ey + e45 * e45 + e135 * e135);
        exk[k] = ex;
        eyk[k] = ey;
    }

    // halo mag entries (164 of them)
    if (tid < 2 * (TX + 2) + 2 * TY) {
        int y, x;
        if (tid < TX + 2) { y = 0; x = tid; }
        else if (tid < 2 * (TX + 2)) { y = TY + 1; x = tid - (TX + 2); }
        else if (tid < 2 * (TX + 2) + TY) { y = tid - 2 * (TX + 2) + 1; x = 0; }
        else { y = tid - (2 * (TX + 2) + TY) + 1; x = TX + 1; }
        int rr, cc;
        if (interior) { rr = y + 1; cc = x + 1; }
        else {
            int r = min(max(i0 - 1 + y, 0), H - 1);
            int c = min(max(j0 - 1 + x, 0), W - 1);
            rr = r - i0 + 2; cc = c - j0 + 2;
        }
        float xmm = fs0[rr - 1][cc - 1], xm0 = fs0[rr - 1][cc], xmp = fs0[rr - 1][cc + 1];
        float x0m = fs0[rr][cc - 1], x0p = fs0[rr][cc + 1];
        float xpm = fs0[rr + 1][cc - 1], xp0 = fs0[rr + 1][cc], xpp = fs0[rr + 1][cc + 1];
        float ex = (xmp - xmm) + 2.0f * (x0p - x0m) + (xpp - xpm);
        float ey = (xpm + 2.0f * xp0 + xpp) - (xmm + 2.0f * xm0 + xmp);
        float e45 = -2.0f * xmm - xm0 - x0m + x0p + xp0 + 2.0f * xpp;
        float e135 = xm0 + 2.0f * xmp - x0m + x0p - 2.0f * xpm - xp0;
        ms[y][x] = sqrtf(ex * ex + ey * ey + e45 * e45 + e135 * e135);
    }
    __syncthreads();

    // 6x3 mag register block covering the 4 pixels' 3x3 neighborhoods
    float msr[6][3];
#pragma unroll
    for (int rr = 0; rr < 6; rr++)
#pragma unroll
        for (int cc = 0; cc < 3; cc++)
            msr[rr][cc] = ms[yb + rr][xl + cc];

    float bmax = 0.0f;
#pragma unroll
    for (int k = 0; k < 4; k++) {
        float ex = exk[k], ey = eyk[k];

        // fast mod-pi line angle
        float ax = fabsf(ex), ay = fabsf(ey);
        float mn = fminf(ax, ay), mxv = fmaxf(ax, ay);
        float tq = (mxv > 0.0f) ? __fdividef(mn, mxv) : 0.0f;
        float pang = atan_poly(tq);
        if (ay > ax) pang = 1.57079632679f - pang;
        bool obtuse = ((__float_as_uint(ex) ^ __float_as_uint(ey)) & 0x80000000u) != 0u;
        float a = obtuse ? PI_F - pang : pang;

        // nearest + second-nearest direction; other two weigh <= e^(-25*pi)
        float fa = a * 1.27323954474f;          // a * 4/pi  in [0,4]
        float nf = floorf(fa + 0.5f);           // 0..4
        float diff = a - nf * 0.78539816340f;
        float delta = fabsf(diff);
        int n = (int)nf & 3;
        int m = ((diff >= 0.0f) ? (int)nf + 1 : (int)nf - 1) & 3;
        float t = __expf(200.0f * delta - 78.5398163397f);   // e^{-100(pi/4-2delta)} <= 1
        float u = __fdividef(1.0f, 1.0f + t);

        float m0 = msr[k + 1][1];
        float n1a = msr[k + 1][0], n1b = msr[k][0], n1c = msr[k][1], n1d = msr[k][2];
        float n2a = msr[k + 1][2], n2b = msr[k + 2][2], n2c = msr[k + 2][1], n2d = msr[k + 2][0];
        float n1n = sel4(n, n1a, n1b, n1c, n1d);
        float n2n = sel4(n, n2a, n2b, n2c, n2d);
        float n1m = sel4(m, n1a, n1b, n1c, n1d);
        float n2m = sel4(m, n2a, n2b, n2c, n2d);

        float g1n = __expf((n1n - m0) * 10.0f);
        float g2n = __expf((n2n - m0) * 10.0f);
        float g1m = __expf((n1m - m0) * 10.0f);
        float g2m = __expf((n2m - m0) * 10.0f);
        float swn = __fdividef(1.0f, 1.0f + g1n + g2n);
        float swm = __fdividef(1.0f, 1.0f + g1m + g2m);
        float s = m0 * u * (swn + t * swm);

        sup[(size_t)p * HW + (i0 + yb + k) * W + (j0 + xl)] = s;
        bmax = fmaxf(bmax, s);

        // median histogram: sob quantized, bins over [0,2)
        float sv = 0.5f * (ax + ay);
        int bin = min((int)(sv * BIN_SCALE), NBINS - 1);
        atomicAdd(&histS[bin], 1u);
    }

    float wv = wave_max(bmax);
    if ((tid & 63) == 0) wred[tid >> 6] = wv;
    __syncthreads();
    if (tid == 0) {
        int bflat = (blockIdx.z * gridDim.y + blockIdx.y) * gridDim.x + blockIdx.x;
        pmax[bflat] = fmaxf(fmaxf(wred[0], wred[1]), fmaxf(wred[2], wred[3]));
    }
    for (int e = tid; e < NBINS; e += 256)
        if (histS[e]) atomicAdd(&hist[p * NBINS + e], histS[e]);
}

// blocks 0..15: per-plane median pick; blocks 16..17: per-set sup max reduce
__global__ void K_stats(const unsigned* __restrict__ hist, const float* __restrict__ pmax,
                        float* __restrict__ medv, float* __restrict__ mx) {
    int b = blockIdx.x;
    int t = threadIdx.x;
    if (b < NP) {
        __shared__ unsigned sums[256];
        const unsigned* hp = hist + b * NBINS;
        unsigned s = 0;
        for (int q = 0; q < NBINS / 256; q++) s += hp[t * (NBINS / 256) + q];
        sums[t] = s;
        __syncthreads();
        for (int off = 1; off < 256; off <<= 1) {
            unsigned v = (t >= off) ? sums[t - off] : 0u;
            __syncthreads();
            sums[t] += v;
            __syncthreads();
        }
        const int k = (HW - 1) / 2;
        unsigned base = (t == 0) ? 0u : sums[t - 1];
        if ((int)base <= k && k < (int)sums[t]) {
            int cum = (int)base;
            int bin = t * (NBINS / 256);
            for (int q = 0; q < NBINS / 256; q++) {
                int c = (int)hp[t * (NBINS / 256) + q];
                if (cum + c > k) { bin = t * (NBINS / 256) + q; break; }
                cum += c;
            }
            medv[b] = ((float)bin + 0.5f) * (1.0f / BIN_SCALE);
        }
    } else {
        __shared__ float red[256];
        int s = b - NP;
        const float* base = pmax + s * HBLK;
        float v = -1e30f;
        for (int i = t; i < HBLK; i += 256) v = fmaxf(v, base[i]);
        red[t] = v;
        __syncthreads();
        for (int sft = 128; sft > 0; sft >>= 1) {
            if (t < sft) red[t] = fmaxf(red[t], red[t + sft]);
            __syncthreads();
        }
        if (t == 0) mx[s] = red[0];
    }
}

// hysteresis combine + dilation + sobel(original) blend; 4 adjacent rows/thread
__global__ void K_result(const float* __restrict__ sup, const float* __restrict__ im1,
                         const float* __restrict__ im2, const float* __restrict__ medv,
                         const float* __restrict__ sg1, const float* __restrict__ ew1,
                         const float* __restrict__ sg2, const float* __restrict__ ew2,
                         const float* __restrict__ mx, float* __restrict__ res,
                         float* __restrict__ prmax, float* __restrict__ prmin) {
    int p = blockIdx.z;
    int s = p >> 3;
    float med = 0.125f * (medv[s * PPS + 0] + medv[s * PPS + 1] + medv[s * PPS + 2] +
                          medv[s * PPS + 3] + medv[s * PPS + 4] + medv[s * PPS + 5] +
                          medv[s * PPS + 6] + medv[s * PPS + 7]);
    float sgin = (s == 0) ? sg1[0] : sg2[0];
    float ewin = (s == 0) ? ew1[0] : ew2[0];
    float sig = 1.0f - 1.0f / (1.0f + __expf(-sgin));
    float lo = fminf(fmaxf((1.0f - sig) * med, 0.001f), 1.0f);
    float hi = fminf(fmaxf((1.0f + sig) * med, 0.001f), 1.0f);
    float wg = 1.0f / (1.0f + __expf(-ewin));
    float m = mx[s];
    float inv = 1.0f / ((m > 0.0f) ? m : 1.0f);

    const float* sp = sup + (size_t)p * HW;
    const float* op = plane_ptr(im1, im2, p);
    int j0 = blockIdx.x * TX, i0 = blockIdx.y * TY;
    __shared__ float hs2[TY + 2][TX + 2];   // hsw(sup_norm - hi), zero outside image
    __shared__ float ssn[TY][TX];           // normalized sup, interior
    __shared__ float og[TY + 2][TX + 2];    // original image, zero outside
    __shared__ float wredx[4], wredn[4];
    int tid = threadIdx.y * 64 + threadIdx.x;

    bool interior = (i0 >= 1) && (i0 + TY <= H - 1) && (j0 >= 1) && (j0 + TX <= W - 1);

    if (interior) {
        const float* spb = sp + (i0 - 1) * W + (j0 - 1);
        const float* opb = op + (i0 - 1) * W + (j0 - 1);
        for (int e = tid; e < (TY + 2) * (TX + 2); e += 256) {
            int y = e / (TX + 2), x = e % (TX + 2);
            float sv = spb[y * W + x] * inv;
            hs2[y][x] = hsw(sv - hi);
            og[y][x] = opb[y * W + x];
            if (y >= 1 && y <= TY && x >= 1 && x <= TX) ssn[y - 1][x - 1] = sv;
        }
    } else {
        for (int e = tid; e < (TY + 2) * (TX + 2); e += 256) {
            int y = e / (TX + 2), x = e % (TX + 2);
            int gi = i0 - 1 + y, gj = j0 - 1 + x;
            float h = 0.0f, o = 0.0f;
            if (gi >= 0 && gi < H && gj >= 0 && gj < W) {
                float sv = sp[gi * W + gj] * inv;
                h = hsw(sv - hi);
                o = op[gi * W + gj];
                if (y >= 1 && y <= TY && x >= 1 && x <= TX) ssn[y - 1][x - 1] = sv;
            }
            hs2[y][x] = h;
            og[y][x] = o;
        }
    }
    __syncthreads();

    int yl = threadIdx.y * 4;
    int xl = threadIdx.x;
    float hrow[6], ddr[6], ssr[6];
#pragma unroll
    for (int k = 0; k < 6; k++) {
        float a = hs2[yl + k][xl], bq = hs2[yl + k][xl + 1], c = hs2[yl + k][xl + 2];
        hrow[k] = a + bq + c;
        float oa = og[yl + k][xl], ob = og[yl + k][xl + 1], oc = og[yl + k][xl + 2];
        ddr[k] = oc - oa;
        ssr[k] = oa + 2.0f * ob + oc;
    }

    float bmx = -1e30f, bmn = 1e30f;
    size_t gbase = (size_t)p * HW + (i0 + yl) * W + (j0 + xl);
#pragma unroll
    for (int k = 0; k < 4; k++) {
        float sn = ssn[yl + k][xl];
        float Sh = hs2[yl + k + 1][xl + 1];
        float Sl = hsw(sn - lo);
        float dil = hrow[k] + hrow[k + 1] + hrow[k + 2];
        float pre = sn * (Sh + Sl) + dil * Sl * (1.0f - Sh);
        float sob = 0.5f * fabsf(ddr[k] + 2.0f * ddr[k + 1] + ddr[k + 2]) +
                    0.5f * fabsf(ssr[k + 2] - ssr[k]);
        float r = (1.0f - wg) * pre + wg * sob;
        res[gbase + (size_t)k * W] = r;
        bmx = fmaxf(bmx, r);
        bmn = fminf(bmn, r);
    }

    float vx = wave_max(bmx), vn = wave_min(bmn);
    if ((tid & 63) == 0) { wredx[tid >> 6] = vx; wredn[tid >> 6] = vn; }
    __syncthreads();
    if (tid == 0) {
        int bflat = (blockIdx.z * gridDim.y + blockIdx.y) * gridDim.x + blockIdx.x;
        prmax[bflat] = fmaxf(fmaxf(wredx[0], wredx[1]), fmaxf(wredx[2], wredx[3]));
        prmin[bflat] = fminf(fminf(wredn[0], wredn[1]), fminf(wredn[2], wredn[3]));
    }
}

// final normalize + combine; folds the partial min/max reduction in; float4 I/O
__global__ void K_final(const float* __restrict__ res, const float* __restrict__ prmax,
                        const float* __restrict__ prmin, float* __restrict__ out) {
    int tid = threadIdx.y * 64 + threadIdx.x;

    // per-block reduction of the 2x2048 partials (reads are L2-resident)
    float vx0 = -1e30f, vn0 = 1e30f, vx1 = -1e30f, vn1 = 1e30f;
    for (int i = tid; i < HBLK; i += 256) {
        vx0 = fmaxf(vx0, prmax[i]);
        vn0 = fminf(vn0, prmin[i]);
        vx1 = fmaxf(vx1, prmax[HBLK + i]);
        vn1 = fminf(vn1, prmin[HBLK + i]);
    }
    vx0 = wave_max(vx0); vn0 = wave_min(vn0);
    vx1 = wave_max(vx1); vn1 = wave_min(vn1);
    __shared__ float sx0[4], sn0[4], sx1[4], sn1[4];
    if ((tid & 63) == 0) {
        int w = tid >> 6;
        sx0[w] = vx0; sn0[w] = vn0; sx1[w] = vx1; sn1[w] = vn1;
    }
    __syncthreads();
    float mx1 = fmaxf(fmaxf(sx0[0], sx0[1]), fmaxf(sx0[2], sx0[3]));
    float mn1 = fminf(fminf(sn0[0], sn0[1]), fminf(sn0[2], sn0[3]));
    float mx2 = fmaxf(fmaxf(sx1[0], sx1[1]), fmaxf(sx1[2], sx1[3]));
    float mn2 = fminf(fminf(sn1[0], sn1[1]), fminf(sn1[2], sn1[3]));
    float is1 = 1.0f / (mx1 - mn1);
    float is2 = 1.0f / (mx2 - mn2);

    int col4 = blockIdx.x * 64 + threadIdx.x;    // float4 column, 0..127
    int i0 = blockIdx.y * 16 + threadIdx.y * 4;  // 4 rows per thread
    int p = blockIdx.z;                          // 0..7
    const float4* r1p = (const float4*)(res + (size_t)p * HW);
    const float4* r2p = (const float4*)(res + (size_t)(p + PPS) * HW);
    float4* outc = (float4*)(out) + (size_t)p * (HW / 4);
    float4* out1 = (float4*)(out) + (size_t)(PPS + p) * (HW / 4);
    float4* out2 = (float4*)(out) + (size_t)(2 * PPS + p) * (HW / 4);

#pragma unroll
    for (int k = 0; k < 4; k++) {
        int row = i0 + k;
        float4 a = r1p[row * (W / 4) + col4];
        float4 b = r2p[row * (W / 4) + col4];
        float4 m1v, m2v, mcv;
        m1v.x = (a.x - mn1) * is1; m1v.y = (a.y - mn1) * is1;
        m1v.z = (a.z - mn1) * is1; m1v.w = (a.w - mn1) * is1;
        m2v.x = (b.x - mn2) * is2; m2v.y = (b.y - mn2) * is2;
        m2v.z = (b.z - mn2) * is2; m2v.w = (b.w - mn2) * is2;
        mcv.x = m1v.x + m2v.x - 2.0f * m1v.x * m2v.x;
        mcv.y = m1v.y + m2v.y - 2.0f * m1v.y * m2v.y;
        mcv.z = m1v.z + m2v.z - 2.0f * m1v.z * m2v.z;
        mcv.w = m1v.w + m2v.w - 2.0f * m1v.w * m2v.w;
        outc[row * (W / 4) + col4] = mcv;
        out1[row * (W / 4) + col4] = m1v;
        out2[row * (W / 4) + col4] = m2v;
    }
}

}  // namespace

extern "C" void kernel_launch(void* const* d_in, const int* in_sizes, int n_in,
                              void* d_out, int out_size, void* d_ws, size_t ws_size,
                              hipStream_t stream) {
    const float* img1 = (const float*)d_in[0];
    const float* img2 = (const float*)d_in[1];
    const float* sg1 = (const float*)d_in[2];
    const float* ew1 = (const float*)d_in[3];
    const float* sg2 = (const float*)d_in[4];
    const float* ew2 = (const float*)d_in[5];
    float* out = (float*)d_out;

    float* A = (float*)d_ws;                             // ping / blurred
    float* B = A + (size_t)NP * HW;                      // pong / res
    float* C = B + (size_t)NP * HW;                      // sup
    unsigned* hist = (unsigned*)(C + (size_t)NP * HW);   // NP*NBINS
    float* medv = (float*)(hist + NP * NBINS);           // 16
    float* mx = medv + NP;
    float* pmax = mx + 2;              // NBLK
    float* prmax = pmax + NBLK;        // NBLK
    float* prmin = prmax + NBLK;       // NBLK

    dim3 blk(64, 4, 1);
    dim3 grdT(W / TX, H / TY, NP);     // dnms / result (4096 blocks)
    dim3 grdS(W / 64, H / STY, NP);    // smooth
    dim3 grdF(W / 256, H / 16, PPS);   // final (512 blocks, float4, 4 rows/thread)
    dim3 mblk(256, 1, 1);

    // adaptive smoothing: 3 iterations  in->A, A->B, B->A  (blurred -> A)
    // first dispatch also zeroes the median histogram
    K_smooth<<<grdS, blk, 0, stream>>>(img1, img2, A, hist);
    K_smooth<<<grdS, blk, 0, stream>>>(A, A + (size_t)PPS * HW, B, nullptr);
    K_smooth<<<grdS, blk, 0, stream>>>(B, B + (size_t)PPS * HW, A, nullptr);

    // fused derivs+NMS+median-hist: A -> sup(C), hist, pmax
    K_dnms<<<grdT, blk, 0, stream>>>(A, C, hist, pmax);

    // per-plane medians + per-set sup max in one dispatch
    K_stats<<<dim3(NP + 2), mblk, 0, stream>>>(hist, pmax, medv, mx);

    // result -> B (+ per-block min/max partials)
    K_result<<<grdT, blk, 0, stream>>>(C, img1, img2, medv, sg1, ew1, sg2, ew2, mx,
                                       B, prmax, prmin);

    // final: fold partial min/max reduce + normalize + combine, float4 I/O
    K_final<<<grdF, blk, 0, stream>>>(B, prmax, prmin, out);
}

// Round 11
// 109.172 us; speedup vs baseline: 1.9166x; 1.0283x over previous
//
#include <hip/hip_runtime.h>

namespace {

constexpr int H = 512;
constexpr int W = 512;
constexpr int HW = H * W;
constexpr int PPS = 8;    // planes per canny set
constexpr int NP = 16;    // total planes (2 sets x 8)
constexpr int TX = 64;    // tile width (dnms/result)
constexpr int TY = 16;    // tile height (dnms/result): 4 adjacent rows/thread
constexpr int STY = 16;   // smooth tile height
constexpr int NBLK = (W / TX) * (H / TY) * NP;   // 4096
constexpr int HBLK = NBLK / 2;                   // 2048 per set
constexpr float PI_F = 3.14159265358979323846f;
constexpr int NBINS = 1024;                 // median bins over [0,2)
constexpr float BIN_SCALE = 512.0f;

__device__ __forceinline__ float hsw(float x) {
    float t = fminf(fmaxf(x + 3.0f, 0.0f), 6.0f);
    return x * t * (1.0f / 6.0f);
}

__device__ __forceinline__ const float* plane_ptr(const float* s1, const float* s2, int p) {
    return (p < PPS) ? (s1 + (size_t)p * HW) : (s2 + (size_t)(p - PPS) * HW);
}

__device__ __forceinline__ float wave_max(float v) {
    for (int o = 32; o > 0; o >>= 1) v = fmaxf(v, __shfl_down(v, o, 64));
    return v;
}
__device__ __forceinline__ float wave_min(float v) {
    for (int o = 32; o > 0; o >>= 1) v = fminf(v, __shfl_down(v, o, 64));
    return v;
}

// minimax atan on [0,1], err ~2e-7
__device__ __forceinline__ float atan_poly(float t) {
    float z = t * t;
    float p = -0.01172120f;
    p = p * z + 0.05265332f;
    p = p * z - 0.11643287f;
    p = p * z + 0.19354346f;
    p = p * z - 0.33262347f;
    p = p * z + 0.99997726f;
    return t * p;
}

// 4-to-1 mux with static code (no runtime-indexed arrays)
__device__ __forceinline__ float sel4(int idx, float v0, float v1, float v2, float v3) {
    float a = (idx & 1) ? v1 : v0;
    float b = (idx & 1) ? v3 : v2;
    return (idx & 2) ? b : a;
}

// One adaptive-smoothing iteration; 16-row tile (base col j0-4, float4 staging).
// First dispatch also zeroes the median histogram (hist != nullptr).
__global__ void K_smooth(const float* __restrict__ s1, const float* __restrict__ s2,
                         float* __restrict__ fout, unsigned* __restrict__ hist) {
    int tid = threadIdx.y * 64 + threadIdx.x;
    if (hist) {
        int bid = (blockIdx.z * gridDim.y + blockIdx.y) * gridDim.x + blockIdx.x;
        if (bid < (NP * NBINS) / 256) hist[bid * 256 + tid] = 0;
    }
    int p = blockIdx.z;
    const float* f = plane_ptr(s1, s2, p);
    int j0 = blockIdx.x * 64, i0 = blockIdx.y * STY;
    __shared__ float fs[STY + 4][72];   // f at (i0-2+y, j0-4+x), clip on border blocks
    __shared__ float ws[STY + 2][66];   // w(clip(i0-1+y), clip(j0-1+x))

    bool interior = (i0 >= 2) && (i0 + STY + 1 <= H - 1) && (j0 >= 4) && (j0 + 67 <= W - 1);

    if (interior) {
        const float* fb = f + (i0 - 2) * W + (j0 - 4);
        for (int e = tid; e < (STY + 4) * 18; e += 256) {
            int y = e / 18, x4 = e % 18;
            float4 v = *(const float4*)(fb + y * W + x4 * 4);
            *(float4*)&fs[y][x4 * 4] = v;
        }
        __syncthreads();
        for (int e = tid; e < (STY + 2) * 66; e += 256) {
            int y = e / 66, x = e % 66;
            float gx = 0.5f * (fs[y + 2][x + 3] - fs[y][x + 3]);
            float gy = 0.5f * (fs[y + 1][x + 4] - fs[y + 1][x + 2]);
            ws[y][x] = __expf(-(gx * gx + gy * gy) * (1.0f / 200.0f));
        }
    } else {
        for (int e = tid; e < (STY + 4) * 72; e += 256) {
            int y = e / 72, x = e % 72;
            int gi = min(max(i0 - 2 + y, 0), H - 1);
            int gj = min(max(j0 - 4 + x, 0), W - 1);
            fs[y][x] = f[gi * W + gj];
        }
        __syncthreads();
        for (int e = tid; e < (STY + 2) * 66; e += 256) {
            int y = e / 66, x = e % 66;
            int r = min(max(i0 - 1 + y, 0), H - 1);   // w evaluated at CLIPPED coords
            int c = min(max(j0 - 1 + x, 0), W - 1);
            int yr = r - (i0 - 2), xc = c - (j0 - 4);
            int ym = max(r - 1, 0) - (i0 - 2), yp = min(r + 1, H - 1) - (i0 - 2);
            int xm = max(c - 1, 0) - (j0 - 4), xp = min(c + 1, W - 1) - (j0 - 4);
            float gx = 0.5f * (fs[yp][xc] - fs[ym][xc]);
            float gy = 0.5f * (fs[yr][xp] - fs[yr][xm]);
            ws[y][x] = __expf(-(gx * gx + gy * gy) * (1.0f / 200.0f));
        }
    }
    __syncthreads();

    int yl = threadIdx.y * 4;
    int xl = threadIdx.x;
    float rn[6], rd[6];
#pragma unroll
    for (int k = 0; k < 6; k++) {
        float w0 = ws[yl + k][xl], w1 = ws[yl + k][xl + 1], w2 = ws[yl + k][xl + 2];
        float fA = fs[yl + k + 1][xl + 3], fB = fs[yl + k + 1][xl + 4], fC = fs[yl + k + 1][xl + 5];
        rn[k] = fA * w0 + fB * w1 + fC * w2;
        rd[k] = w0 + w1 + w2;
    }
    size_t base = (size_t)p * HW + (i0 + yl) * W + (j0 + xl);
#pragma unroll
    for (int k = 0; k < 4; k++) {
        fout[base + (size_t)k * W] =
            (rn[k] + rn[k + 1] + rn[k + 2]) / fmaxf(rd[k] + rd[k + 1] + rd[k + 2], 1e-8f);
    }
}

// fused derivatives + NMS (2-direction softmax) + median histogram.
// Interior derivatives live in registers; only mag goes through LDS.
// Base col j0-4, float4 staging; 2 wave-private histogram copies.
__global__ void K_dnms(const float* __restrict__ blur, float* __restrict__ sup,
                       unsigned* __restrict__ hist, float* __restrict__ pmax) {
    int p = blockIdx.z;
    const float* f = blur + (size_t)p * HW;
    int j0 = blockIdx.x * TX, i0 = blockIdx.y * TY;
    __shared__ float fs0[TY + 4][72];   // ZERO-padded blur at (i0-2+y, j0-4+x)
    __shared__ float ms[TY + 2][TX + 2];
    __shared__ unsigned histS[2][NBINS];
    __shared__ float wred[4];
    int tid = threadIdx.y * 64 + threadIdx.x;
    int hsel = threadIdx.y >> 1;   // waves 0-1 -> copy 0, waves 2-3 -> copy 1

    bool interior = (i0 >= 2) && (i0 + TY + 1 <= H - 1) && (j0 >= 4) && (j0 + 67 <= W - 1);

    for (int e = tid; e < 2 * NBINS; e += 256) histS[e >> 10][e & (NBINS - 1)] = 0;
    if (interior) {
        const float* fb = f + (i0 - 2) * W + (j0 - 4);
        for (int e = tid; e < (TY + 4) * 18; e += 256) {
            int y = e / 18, x4 = e % 18;
            float4 v = *(const float4*)(fb + y * W + x4 * 4);
            *(float4*)&fs0[y][x4 * 4] = v;
        }
    } else {
        for (int e = tid; e < (TY + 4) * 72; e += 256) {
            int y = e / 72, x = e % 72;
            int gi = i0 - 2 + y, gj = j0 - 4 + x;
            fs0[y][x] = (gi >= 0 && gi < H && gj >= 0 && gj < W) ? f[gi * W + gj] : 0.0f;
        }
    }
    __syncthreads();

    int xl = threadIdx.x;
    int yb = threadIdx.y * 4;

    // interior pixels: this thread's 4 adjacent rows; derivatives in registers
    float fv[6][3];
#pragma unroll
    for (int rr = 0; rr < 6; rr++)
#pragma unroll
        for (int cc = 0; cc < 3; cc++)
            fv[rr][cc] = fs0[yb + 1 + rr][xl + 3 + cc];

    float exk[4], eyk[4];
#pragma unroll
    for (int k = 0; k < 4; k++) {
        float xmm = fv[k][0], xm0 = fv[k][1], xmp = fv[k][2];
        float x0m = fv[k + 1][0], x0p = fv[k + 1][2];
        float xpm = fv[k + 2][0], xp0 = fv[k + 2][1], xpp = fv[k + 2][2];
        float ex = (xmp - xmm) + 2.0f * (x0p - x0m) + (xpp - xpm);
        float ey = (xpm + 2.0f * xp0 + xpp) - (xmm + 2.0f * xm0 + xmp);
        float e45 = -2.0f * xmm - xm0 - x0m + x0p + xp0 + 2.0f * xpp;
        float e135 = xm0 + 2.0f * xmp - x0m + x0p - 2.0f * xpm - xp0;
        ms[yb + 1 + k][xl + 1] = sqrtf(ex * ex + ey * ey + e45 * e45 + e135 * e135);
        exk[k] = ex;
        eyk[k] = ey;
    }

    // halo mag entries (164 of them)
    if (tid < 2 * (TX + 2) + 2 * TY) {
        int y, x;
        if (tid < TX + 2) { y = 0; x = tid; }
        else if (tid < 2 * (TX + 2)) { y = TY + 1; x = tid - (TX + 2); }
        else if (tid < 2 * (TX + 2) + TY) { y = tid - 2 * (TX + 2) + 1; x = 0; }
        else { y = tid - (2 * (TX + 2) + TY) + 1; x = TX + 1; }
        int rr, cc;
        if (interior) { rr = y + 1; cc = x + 3; }
        else {
            int r = min(max(i0 - 1 + y, 0), H - 1);
            int c = min(max(j0 - 1 + x, 0), W - 1);
            rr = r - i0 + 2; cc = c - j0 + 4;
        }
        float xmm = fs0[rr - 1][cc - 1], xm0 = fs0[rr - 1][cc], xmp = fs0[rr - 1][cc + 1];
        float x0m = fs0[rr][cc - 1], x0p = fs0[rr][cc + 1];
        float xpm = fs0[rr + 1][cc - 1], xp0 = fs0[rr + 1][cc], xpp = fs0[rr + 1][cc + 1];
        float ex = (xmp - xmm) + 2.0f * (x0p - x0m) + (xpp - xpm);
        float ey = (xpm + 2.0f * xp0 + xpp) - (xmm + 2.0f * xm0 + xmp);
        float e45 = -2.0f * xmm - xm0 - x0m + x0p + xp0 + 2.0f * xpp;
        float e135 = xm0 + 2.0f * xmp - x0m + x0p - 2.0f * xpm - xp0;
        ms[y][x] = sqrtf(ex * ex + ey * ey + e45 * e45 + e135 * e135);
    }
    __syncthreads();

    // 6x3 mag register block covering the 4 pixels' 3x3 neighborhoods
    float msr[6][3];
#pragma unroll
    for (int rr = 0; rr < 6; rr++)
#pragma unroll
        for (int cc = 0; cc < 3; cc++)
            msr[rr][cc] = ms[yb + rr][xl + cc];

    float bmax = 0.0f;
#pragma unroll
    for (int k = 0; k < 4; k++) {
        float ex = exk[k], ey = eyk[k];

        // fast mod-pi line angle
        float ax = fabsf(ex), ay = fabsf(ey);
        float mn = fminf(ax, ay), mxv = fmaxf(ax, ay);
        float tq = (mxv > 0.0f) ? __fdividef(mn, mxv) : 0.0f;
        float pang = atan_poly(tq);
        if (ay > ax) pang = 1.57079632679f - pang;
        bool obtuse = ((__float_as_uint(ex) ^ __float_as_uint(ey)) & 0x80000000u) != 0u;
        float a = obtuse ? PI_F - pang : pang;

        // nearest + second-nearest direction; other two weigh <= e^(-25*pi)
        float fa = a * 1.27323954474f;          // a * 4/pi  in [0,4]
        float nf = floorf(fa + 0.5f);           // 0..4
        float diff = a - nf * 0.78539816340f;
        float delta = fabsf(diff);
        int n = (int)nf & 3;
        int m = ((diff >= 0.0f) ? (int)nf + 1 : (int)nf - 1) & 3;
        float t = __expf(200.0f * delta - 78.5398163397f);   // e^{-100(pi/4-2delta)} <= 1
        float u = __fdividef(1.0f, 1.0f + t);

        float m0 = msr[k + 1][1];
        float n1a = msr[k + 1][0], n1b = msr[k][0], n1c = msr[k][1], n1d = msr[k][2];
        float n2a = msr[k + 1][2], n2b = msr[k + 2][2], n2c = msr[k + 2][1], n2d = msr[k + 2][0];
        float n1n = sel4(n, n1a, n1b, n1c, n1d);
        float n2n = sel4(n, n2a, n2b, n2c, n2d);
        float n1m = sel4(m, n1a, n1b, n1c, n1d);
        float n2m = sel4(m, n2a, n2b, n2c, n2d);

        float g1n = __expf((n1n - m0) * 10.0f);
        float g2n = __expf((n2n - m0) * 10.0f);
        float g1m = __expf((n1m - m0) * 10.0f);
        float g2m = __expf((n2m - m0) * 10.0f);
        float swn = __fdividef(1.0f, 1.0f + g1n + g2n);
        float swm = __fdividef(1.0f, 1.0f + g1m + g2m);
        float s = m0 * u * (swn + t * swm);

        sup[(size_t)p * HW + (i0 + yb + k) * W + (j0 + xl)] = s;
        bmax = fmaxf(bmax, s);

        // median histogram: sob quantized, bins over [0,2); wave-private copy
        float sv = 0.5f * (ax + ay);
        int bin = min((int)(sv * BIN_SCALE), NBINS - 1);
        atomicAdd(&histS[hsel][bin], 1u);
    }

    float wv = wave_max(bmax);
    if ((tid & 63) == 0) wred[tid >> 6] = wv;
    __syncthreads();
    if (tid == 0) {
        int bflat = (blockIdx.z * gridDim.y + blockIdx.y) * gridDim.x + blockIdx.x;
        pmax[bflat] = fmaxf(fmaxf(wred[0], wred[1]), fmaxf(wred[2], wred[3]));
    }
    for (int e = tid; e < NBINS; e += 256) {
        unsigned v = histS[0][e] + histS[1][e];
        if (v) atomicAdd(&hist[p * NBINS + e], v);
    }
}

// blocks 0..15: per-plane median pick; blocks 16..17: per-set sup max reduce
__global__ void K_stats(const unsigned* __restrict__ hist, const float* __restrict__ pmax,
                        float* __restrict__ medv, float* __restrict__ mx) {
    int b = blockIdx.x;
    int t = threadIdx.x;
    if (b < NP) {
        __shared__ unsigned sums[256];
        const unsigned* hp = hist + b * NBINS;
        unsigned s = 0;
        for (int q = 0; q < NBINS / 256; q++) s += hp[t * (NBINS / 256) + q];
        sums[t] = s;
        __syncthreads();
        for (int off = 1; off < 256; off <<= 1) {
            unsigned v = (t >= off) ? sums[t - off] : 0u;
            __syncthreads();
            sums[t] += v;
            __syncthreads();
        }
        const int k = (HW - 1) / 2;
        unsigned base = (t == 0) ? 0u : sums[t - 1];
        if ((int)base <= k && k < (int)sums[t]) {
            int cum = (int)base;
            int bin = t * (NBINS / 256);
            for (int q = 0; q < NBINS / 256; q++) {
                int c = (int)hp[t * (NBINS / 256) + q];
                if (cum + c > k) { bin = t * (NBINS / 256) + q; break; }
                cum += c;
            }
            medv[b] = ((float)bin + 0.5f) * (1.0f / BIN_SCALE);
        }
    } else {
        __shared__ float red[256];
        int s = b - NP;
        const float* base = pmax + s * HBLK;
        float v = -1e30f;
        for (int i = t; i < HBLK; i += 256) v = fmaxf(v, base[i]);
        red[t] = v;
        __syncthreads();
        for (int sft = 128; sft > 0; sft >>= 1) {
            if (t < sft) red[t] = fmaxf(red[t], red[t + sft]);
            __syncthreads();
        }
        if (t == 0) mx[s] = red[0];
    }
}

// hysteresis combine + dilation + sobel(original) blend; base col j0-4, float4 staging
__global__ void K_result(const float* __restrict__ sup, const float* __restrict__ im1,
                         const float* __restrict__ im2, const float* __restrict__ medv,
                         const float* __restrict__ sg1, const float* __restrict__ ew1,
                         const float* __restrict__ sg2, const float* __restrict__ ew2,
                         const float* __restrict__ mx, float* __restrict__ res,
                         float* __restrict__ prmax, float* __restrict__ prmin) {
    int p = blockIdx.z;
    int s = p >> 3;
    float med = 0.125f * (medv[s * PPS + 0] + medv[s * PPS + 1] + medv[s * PPS + 2] +
                          medv[s * PPS + 3] + medv[s * PPS + 4] + medv[s * PPS + 5] +
                          medv[s * PPS + 6] + medv[s * PPS + 7]);
    float sgin = (s == 0) ? sg1[0] : sg2[0];
    float ewin = (s == 0) ? ew1[0] : ew2[0];
    float sig = 1.0f - 1.0f / (1.0f + __expf(-sgin));
    float lo = fminf(fmaxf((1.0f - sig) * med, 0.001f), 1.0f);
    float hi = fminf(fmaxf((1.0f + sig) * med, 0.001f), 1.0f);
    float wg = 1.0f / (1.0f + __expf(-ewin));
    float m = mx[s];
    float inv = 1.0f / ((m > 0.0f) ? m : 1.0f);

    const float* sp = sup + (size_t)p * HW;
    const float* op = plane_ptr(im1, im2, p);
    int j0 = blockIdx.x * TX, i0 = blockIdx.y * TY;
    __shared__ float hs2[TY + 2][72];   // hsw(sup_norm - hi) at (i0-1+y, j0-4+x), 0 outside
    __shared__ float og[TY + 2][72];    // original image, 0 outside
    __shared__ float ssn[TY][TX];       // normalized sup, interior pixels
    __shared__ float wredx[4], wredn[4];
    int tid = threadIdx.y * 64 + threadIdx.x;

    bool interior = (i0 >= 1) && (i0 + TY <= H - 1) && (j0 >= 4) && (j0 + 67 <= W - 1);

    if (interior) {
        const float* spb = sp + (i0 - 1) * W + (j0 - 4);
        const float* opb = op + (i0 - 1) * W + (j0 - 4);
        for (int e = tid; e < (TY + 2) * 18; e += 256) {
            int y = e / 18, x4 = e % 18;
            float4 a = *(const float4*)(spb + y * W + x4 * 4);
            float4 o = *(const float4*)(opb + y * W + x4 * 4);
            float sv0 = a.x * inv, sv1 = a.y * inv, sv2 = a.z * inv, sv3 = a.w * inv;
            float4 hv;
            hv.x = hsw(sv0 - hi); hv.y = hsw(sv1 - hi);
            hv.z = hsw(sv2 - hi); hv.w = hsw(sv3 - hi);
            *(float4*)&hs2[y][x4 * 4] = hv;
            *(float4*)&og[y][x4 * 4] = o;
            if (y >= 1 && y <= TY) {
                int c0 = x4 * 4;
                if (c0 + 0 >= 4 && c0 + 0 <= 67) ssn[y - 1][c0 - 4] = sv0;
                if (c0 + 1 >= 4 && c0 + 1 <= 67) ssn[y - 1][c0 - 3] = sv1;
                if (c0 + 2 >= 4 && c0 + 2 <= 67) ssn[y - 1][c0 - 2] = sv2;
                if (c0 + 3 >= 4 && c0 + 3 <= 67) ssn[y - 1][c0 - 1] = sv3;
            }
        }
    } else {
        for (int e = tid; e < (TY + 2) * 72; e += 256) {
            int y = e / 72, x = e % 72;
            int gi = i0 - 1 + y, gj = j0 - 4 + x;
            float h = 0.0f, o = 0.0f;
            if (gi >= 0 && gi < H && gj >= 0 && gj < W) {
                float sv = sp[gi * W + gj] * inv;
                h = hsw(sv - hi);
                o = op[gi * W + gj];
                if (y >= 1 && y <= TY && x >= 4 && x <= 67) ssn[y - 1][x - 4] = sv;
            }
            hs2[y][x] = h;
            og[y][x] = o;
        }
    }
    __syncthreads();

    int yl = threadIdx.y * 4;
    int xl = threadIdx.x;
    float hrow[6], ddr[6], ssr[6];
#pragma unroll
    for (int k = 0; k < 6; k++) {
        float a = hs2[yl + k][xl + 3], bq = hs2[yl + k][xl + 4], c = hs2[yl + k][xl + 5];
        hrow[k] = a + bq + c;
        float oa = og[yl + k][xl + 3], ob = og[yl + k][xl + 4], oc = og[yl + k][xl + 5];
        ddr[k] = oc - oa;
        ssr[k] = oa + 2.0f * ob + oc;
    }

    float bmx = -1e30f, bmn = 1e30f;
    size_t gbase = (size_t)p * HW + (i0 + yl) * W + (j0 + xl);
#pragma unroll
    for (int k = 0; k < 4; k++) {
        float sn = ssn[yl + k][xl];
        float Sh = hs2[yl + k + 1][xl + 4];
        float Sl = hsw(sn - lo);
        float dil = hrow[k] + hrow[k + 1] + hrow[k + 2];
        float pre = sn * (Sh + Sl) + dil * Sl * (1.0f - Sh);
        float sob = 0.5f * fabsf(ddr[k] + 2.0f * ddr[k + 1] + ddr[k + 2]) +
                    0.5f * fabsf(ssr[k + 2] - ssr[k]);
        float r = (1.0f - wg) * pre + wg * sob;
        res[gbase + (size_t)k * W] = r;
        bmx = fmaxf(bmx, r);
        bmn = fminf(bmn, r);
    }

    float vx = wave_max(bmx), vn = wave_min(bmn);
    if ((tid & 63) == 0) { wredx[tid >> 6] = vx; wredn[tid >> 6] = vn; }
    __syncthreads();
    if (tid == 0) {
        int bflat = (blockIdx.z * gridDim.y + blockIdx.y) * gridDim.x + blockIdx.x;
        prmax[bflat] = fmaxf(fmaxf(wredx[0], wredx[1]), fmaxf(wredx[2], wredx[3]));
        prmin[bflat] = fminf(fminf(wredn[0], wredn[1]), fminf(wredn[2], wredn[3]));
    }
}

// final normalize + combine; folds the partial min/max reduction in; float4 I/O
__global__ void K_final(const float* __restrict__ res, const float* __restrict__ prmax,
                        const float* __restrict__ prmin, float* __restrict__ out) {
    int tid = threadIdx.y * 64 + threadIdx.x;

    float vx0 = -1e30f, vn0 = 1e30f, vx1 = -1e30f, vn1 = 1e30f;
    for (int i = tid; i < HBLK; i += 256) {
        vx0 = fmaxf(vx0, prmax[i]);
        vn0 = fminf(vn0, prmin[i]);
        vx1 = fmaxf(vx1, prmax[HBLK + i]);
        vn1 = fminf(vn1, prmin[HBLK + i]);
    }
    vx0 = wave_max(vx0); vn0 = wave_min(vn0);
    vx1 = wave_max(vx1); vn1 = wave_min(vn1);
    __shared__ float sx0[4], sn0[4], sx1[4], sn1[4];
    if ((tid & 63) == 0) {
        int w = tid >> 6;
        sx0[w] = vx0; sn0[w] = vn0; sx1[w] = vx1; sn1[w] = vn1;
    }
    __syncthreads();
    float mx1 = fmaxf(fmaxf(sx0[0], sx0[1]), fmaxf(sx0[2], sx0[3]));
    float mn1 = fminf(fminf(sn0[0], sn0[1]), fminf(sn0[2], sn0[3]));
    float mx2 = fmaxf(fmaxf(sx1[0], sx1[1]), fmaxf(sx1[2], sx1[3]));
    float mn2 = fminf(fminf(sn1[0], sn1[1]), fminf(sn1[2], sn1[3]));
    float is1 = 1.0f / (mx1 - mn1);
    float is2 = 1.0f / (mx2 - mn2);

    int col4 = blockIdx.x * 64 + threadIdx.x;    // float4 column, 0..127
    int i0 = blockIdx.y * 16 + threadIdx.y * 4;  // 4 rows per thread
    int p = blockIdx.z;                          // 0..7
    const float4* r1p = (const float4*)(res + (size_t)p * HW);
    const float4* r2p = (const float4*)(res + (size_t)(p + PPS) * HW);
    float4* outc = (float4*)(out) + (size_t)p * (HW / 4);
    float4* out1 = (float4*)(out) + (size_t)(PPS + p) * (HW / 4);
    float4* out2 = (float4*)(out) + (size_t)(2 * PPS + p) * (HW / 4);

#pragma unroll
    for (int k = 0; k < 4; k++) {
        int row = i0 + k;
        float4 a = r1p[row * (W / 4) + col4];
        float4 b = r2p[row * (W / 4) + col4];
        float4 m1v, m2v, mcv;
        m1v.x = (a.x - mn1) * is1; m1v.y = (a.y - mn1) * is1;
        m1v.z = (a.z - mn1) * is1; m1v.w = (a.w - mn1) * is1;
        m2v.x = (b.x - mn2) * is2; m2v.y = (b.y - mn2) * is2;
        m2v.z = (b.z - mn2) * is2; m2v.w = (b.w - mn2) * is2;
        mcv.x = m1v.x + m2v.x - 2.0f * m1v.x * m2v.x;
        mcv.y = m1v.y + m2v.y - 2.0f * m1v.y * m2v.y;
        mcv.z = m1v.z + m2v.z - 2.0f * m1v.z * m2v.z;
        mcv.w = m1v.w + m2v.w - 2.0f * m1v.w * m2v.w;
        outc[row * (W / 4) + col4] = mcv;
        out1[row * (W / 4) + col4] = m1v;
        out2[row * (W / 4) + col4] = m2v;
    }
}

}  // namespace

extern "C" void kernel_launch(void* const* d_in, const int* in_sizes, int n_in,
                              void* d_out, int out_size, void* d_ws, size_t ws_size,
                              hipStream_t stream) {
    const float* img1 = (const float*)d_in[0];
    const float* img2 = (const float*)d_in[1];
    const float* sg1 = (const float*)d_in[2];
    const float* ew1 = (const float*)d_in[3];
    const float* sg2 = (const float*)d_in[4];
    const float* ew2 = (const float*)d_in[5];
    float* out = (float*)d_out;

    float* A = (float*)d_ws;                             // ping / blurred
    float* B = A + (size_t)NP * HW;                      // pong / res
    float* C = B + (size_t)NP * HW;                      // sup
    unsigned* hist = (unsigned*)(C + (size_t)NP * HW);   // NP*NBINS
    float* medv = (float*)(hist + NP * NBINS);           // 16
    float* mx = medv + NP;
    float* pmax = mx + 2;              // NBLK
    float* prmax = pmax + NBLK;        // NBLK
    float* prmin = prmax + NBLK;       // NBLK

    dim3 blk(64, 4, 1);
    dim3 grdT(W / TX, H / TY, NP);     // dnms / result (4096 blocks)
    dim3 grdS(W / 64, H / STY, NP);    // smooth
    dim3 grdF(W / 256, H / 16, PPS);   // final (512 blocks, float4, 4 rows/thread)
    dim3 mblk(256, 1, 1);

    // adaptive smoothing: 3 iterations  in->A, A->B, B->A  (blurred -> A)
    // first dispatch also zeroes the median histogram
    K_smooth<<<grdS, blk, 0, stream>>>(img1, img2, A, hist);
    K_smooth<<<grdS, blk, 0, stream>>>(A, A + (size_t)PPS * HW, B, nullptr);
    K_smooth<<<grdS, blk, 0, stream>>>(B, B + (size_t)PPS * HW, A, nullptr);

    // fused derivs+NMS+median-hist: A -> sup(C), hist, pmax
    K_dnms<<<grdT, blk, 0, stream>>>(A, C, hist, pmax);

    // per-plane medians + per-set sup max in one dispatch
    K_stats<<<dim3(NP + 2), mblk, 0, stream>>>(hist, pmax, medv, mx);

    // result -> B (+ per-block min/max partials)
    K_result<<<grdT, blk, 0, stream>>>(C, img1, img2, medv, sg1, ew1, sg2, ew2, mx,
                                       B, prmax, prmin);

    // final: fold partial min/max reduce + normalize + combine, float4 I/O
    K_final<<<grdF, blk, 0, stream>>>(B, prmax, prmin, out);
}